// Round 1
// baseline (580.427 us; speedup 1.0000x reference)
//
#include <hip/hip_runtime.h>

// ---------------------------------------------------------------------------
// RiskAttention: q/k/v proj -> lexicon relevance -> self-attn -> boost -> LN -> pool
// B=16 S=1024 D=1024 R=512 E=768, fp32 in/out, bf16 MFMA compute.
// Round 0: batched 128x128 BT-GEMM (m97 structure), separate glue kernels.
// ---------------------------------------------------------------------------

#define BB 16
#define SS 1024
#define DD 1024
#define RR 512
#define EE 768

typedef __attribute__((ext_vector_type(4))) float f32x4;
typedef __attribute__((ext_vector_type(8))) __bf16 bf16x8;

typedef __attribute__((address_space(1))) const void g_void;
typedef __attribute__((address_space(3))) void l_void;

__device__ __forceinline__ ushort f2b(float x) {
    unsigned u = __float_as_uint(x);
    u += 0x7fffu + ((u >> 16) & 1u);   // RNE
    return (ushort)(u >> 16);
}

// ---------------------------------------------------------------------------
// Casts
// ---------------------------------------------------------------------------
__global__ void cast_f32_bf16(const float* __restrict__ in, ushort* __restrict__ out, long n4) {
    long i = (long)blockIdx.x * blockDim.x + threadIdx.x;
    if (i >= n4) return;
    float4 v = *(const float4*)(in + i * 4);
    ushort4 o;
    o.x = f2b(v.x); o.y = f2b(v.y); o.z = f2b(v.z); o.w = f2b(v.w);
    *(ushort4*)(out + i * 4) = o;
}

// in [rows, cols] fp32 -> out [cols, rows] bf16
__global__ void transpose_cast(const float* __restrict__ in, ushort* __restrict__ out,
                               int rows, int cols) {
    __shared__ float tile[32][33];
    const int bx = blockIdx.x * 32;   // col base
    const int by = blockIdx.y * 32;   // row base
    const int tx = threadIdx.x;       // 0..31
    const int ty = threadIdx.y;       // 0..7
#pragma unroll
    for (int i = 0; i < 32; i += 8)
        tile[ty + i][tx] = in[(long)(by + ty + i) * cols + bx + tx];
    __syncthreads();
#pragma unroll
    for (int i = 0; i < 32; i += 8)
        out[(long)(bx + ty + i) * rows + by + tx] = f2b(tile[tx][ty + i]);
}

// ---------------------------------------------------------------------------
// Batched BT-GEMM: C[z][m][n] = sum_k A[z][m][k] * B[z][n][k]  (both bf16 row-major)
// 128x128 tile, BK=32, 4 waves (2x2 of 64x64), 16x16x32 bf16 MFMA,
// global_load_lds width-16 staging (m97 structure).
// Epilogue: optional scale (*scale_ptr), bias per col (1) / per row (2),
// optional per-row scale (boost), output bf16 or fp32.
// ---------------------------------------------------------------------------
template <int BIAS_MODE, bool OUT_BF16, bool ROWSCALE>
__global__ __launch_bounds__(256) void gemm_bt(
    const ushort* __restrict__ A, const ushort* __restrict__ B, void* __restrict__ C,
    const float* __restrict__ bias, const float* __restrict__ rowscale,
    const float* __restrict__ scale_ptr,
    int N, int K, int M, long sA, long sB, long sC)
{
    __shared__ ushort lA[128 * 32];
    __shared__ ushort lB[128 * 32];
    const int tid  = threadIdx.x;
    const int wave = tid >> 6;
    const int lane = tid & 63;
    const int bn = blockIdx.x, bm = blockIdx.y, bz = blockIdx.z;
    const ushort* Ab = A + (long)bz * sA + (long)bm * 128 * K;
    const ushort* Bb = B + (long)bz * sB + (long)bn * 128 * K;
    const int wm = wave >> 1, wn = wave & 1;

    f32x4 acc[4][4];
#pragma unroll
    for (int i = 0; i < 4; ++i)
#pragma unroll
        for (int j = 0; j < 4; ++j) acc[i][j] = (f32x4){0.f, 0.f, 0.f, 0.f};

    const int srow_base = (lane >> 2);        // 0..15 within chunk
    const int sk = (lane & 3) * 8;            // k element offset of this lane's 16B

    for (int kt = 0; kt < K; kt += 32) {
        __syncthreads();   // previous iteration's LDS reads done
#pragma unroll
        for (int j = 0; j < 2; ++j) {
            const int c   = wave * 2 + j;             // chunk 0..7 (16 rows each)
            const int row = c * 16 + srow_base;
            const long go = (long)row * K + kt + sk;
            __builtin_amdgcn_global_load_lds((g_void*)(Ab + go), (l_void*)(lA + c * 512), 16, 0, 0);
            __builtin_amdgcn_global_load_lds((g_void*)(Bb + go), (l_void*)(lB + c * 512), 16, 0, 0);
        }
        __syncthreads();   // staging complete (vmcnt drained at barrier)

        bf16x8 af[4], bfr[4];
        const int r  = lane & 15;
        const int h8 = (lane >> 4) * 8;       // k-slot offset (8 elems = 16B)
#pragma unroll
        for (int mi = 0; mi < 4; ++mi)
            af[mi] = *(const bf16x8*)(lA + (wm * 64 + mi * 16 + r) * 32 + h8);
#pragma unroll
        for (int ni = 0; ni < 4; ++ni)
            bfr[ni] = *(const bf16x8*)(lB + (wn * 64 + ni * 16 + r) * 32 + h8);
#pragma unroll
        for (int mi = 0; mi < 4; ++mi)
#pragma unroll
            for (int ni = 0; ni < 4; ++ni)
                acc[mi][ni] = __builtin_amdgcn_mfma_f32_16x16x32_bf16(
                    af[mi], bfr[ni], acc[mi][ni], 0, 0, 0);
    }

    const float scale = scale_ptr ? *scale_ptr : 1.0f;
    const int r  = lane & 15;
    const int g4 = (lane >> 4) * 4;
#pragma unroll
    for (int mi = 0; mi < 4; ++mi) {
        const int row0 = bm * 128 + wm * 64 + mi * 16 + g4;
#pragma unroll
        for (int ni = 0; ni < 4; ++ni) {
            const int col = bn * 128 + wn * 64 + ni * 16 + r;
            float bcol = (BIAS_MODE == 1) ? bias[col] : 0.0f;
#pragma unroll
            for (int j = 0; j < 4; ++j) {
                float v = acc[mi][ni][j] * scale;
                if (BIAS_MODE == 1) v += bcol;
                if (BIAS_MODE == 2) v += bias[row0 + j];
                if (ROWSCALE)       v *= rowscale[(long)bz * M + row0 + j];
                const long idx = (long)bz * sC + (long)(row0 + j) * N + col;
                if (OUT_BF16) ((ushort*)C)[idx] = f2b(v);
                else          ((float*)C)[idx]  = v;
            }
        }
    }
}

// ---------------------------------------------------------------------------
// rowmax over 512 + sigmoid -> boost = 1 + sigmoid(max)
// ---------------------------------------------------------------------------
__global__ void rowmax_boost(const float* __restrict__ punt, float* __restrict__ boost) {
    const long row = blockIdx.x;
    const int tid = threadIdx.x;
    __shared__ float sm[4];
    float m = fmaxf(punt[row * RR + tid], punt[row * RR + tid + 256]);
#pragma unroll
    for (int o = 32; o > 0; o >>= 1) m = fmaxf(m, __shfl_down(m, o));
    if ((tid & 63) == 0) sm[tid >> 6] = m;
    __syncthreads();
    if (tid == 0) {
        m = fmaxf(fmaxf(sm[0], sm[1]), fmaxf(sm[2], sm[3]));
        boost[row] = 1.0f + 1.0f / (1.0f + __expf(-m));
    }
}

// ---------------------------------------------------------------------------
// Row softmax: fp32 [rows,1024] -> bf16 [rows,1024]
// ---------------------------------------------------------------------------
__global__ void softmax_rows(const float* __restrict__ S, ushort* __restrict__ P) {
    const long row = blockIdx.x;
    const int tid = threadIdx.x;
    __shared__ float sm[4];
    float4 x = *(const float4*)(S + row * 1024 + tid * 4);
    float m = fmaxf(fmaxf(x.x, x.y), fmaxf(x.z, x.w));
#pragma unroll
    for (int o = 32; o > 0; o >>= 1) m = fmaxf(m, __shfl_down(m, o));
    if ((tid & 63) == 0) sm[tid >> 6] = m;
    __syncthreads();
    m = fmaxf(fmaxf(sm[0], sm[1]), fmaxf(sm[2], sm[3]));
    __syncthreads();
    float e0 = __expf(x.x - m), e1 = __expf(x.y - m);
    float e2 = __expf(x.z - m), e3 = __expf(x.w - m);
    float s = e0 + e1 + e2 + e3;
#pragma unroll
    for (int o = 32; o > 0; o >>= 1) s += __shfl_down(s, o);
    if ((tid & 63) == 0) sm[tid >> 6] = s;
    __syncthreads();
    s = sm[0] + sm[1] + sm[2] + sm[3];
    const float inv = 1.0f / s;
    ushort4 o4;
    o4.x = f2b(e0 * inv); o4.y = f2b(e1 * inv);
    o4.z = f2b(e2 * inv); o4.w = f2b(e3 * inv);
    *(ushort4*)(P + row * 1024 + tid * 4) = o4;
}

// ---------------------------------------------------------------------------
// LayerNorm over D + mean-pool over S (atomicAdd into out[b][d])
// grid (schunk=16, b=16), block 256; each block: 64 rows
// ---------------------------------------------------------------------------
__global__ void ln_pool(const float* __restrict__ x, const float* __restrict__ gamma,
                        const float* __restrict__ beta, float* __restrict__ out) {
    const int b = blockIdx.y, chunk = blockIdx.x, tid = threadIdx.x;
    __shared__ float sm[8];
    float4 g  = *(const float4*)(gamma + tid * 4);
    float4 be = *(const float4*)(beta + tid * 4);
    float a0 = 0, a1 = 0, a2 = 0, a3 = 0;
    for (int s = chunk * 64; s < chunk * 64 + 64; ++s) {
        float4 xv = *(const float4*)(x + ((long)b * SS + s) * DD + tid * 4);
        float ls = xv.x + xv.y + xv.z + xv.w;
        float lq = xv.x * xv.x + xv.y * xv.y + xv.z * xv.z + xv.w * xv.w;
#pragma unroll
        for (int o = 32; o > 0; o >>= 1) { ls += __shfl_down(ls, o); lq += __shfl_down(lq, o); }
        if ((tid & 63) == 0) { sm[(tid >> 6) * 2] = ls; sm[(tid >> 6) * 2 + 1] = lq; }
        __syncthreads();
        const float ts = sm[0] + sm[2] + sm[4] + sm[6];
        const float tq = sm[1] + sm[3] + sm[5] + sm[7];
        __syncthreads();
        const float mu  = ts * (1.0f / DD);
        const float var = tq * (1.0f / DD) - mu * mu;
        const float rs  = rsqrtf(var + 1e-5f);
        a0 += (xv.x - mu) * rs * g.x + be.x;
        a1 += (xv.y - mu) * rs * g.y + be.y;
        a2 += (xv.z - mu) * rs * g.z + be.z;
        a3 += (xv.w - mu) * rs * g.w + be.w;
    }
    const float is = 1.0f / SS;
    atomicAdd(out + (long)b * DD + tid * 4 + 0, a0 * is);
    atomicAdd(out + (long)b * DD + tid * 4 + 1, a1 * is);
    atomicAdd(out + (long)b * DD + tid * 4 + 2, a2 * is);
    atomicAdd(out + (long)b * DD + tid * 4 + 3, a3 * is);
}

// ---------------------------------------------------------------------------
// Workspace layout (bytes)
// ---------------------------------------------------------------------------
#define OFF_XBF   0ul            /* 32MB bf16 X [16384,1024]; later reused for P */
#define OFF_WQT   33554432ul     /* 2MB  Wq^T [1024,1024] */
#define OFF_WKT   35651584ul
#define OFF_WVT   37748736ul
#define OFF_WPRT  39845888ul     /* 1.5MB Wpr^T [1024,768] */
#define OFF_EMBB  41418752ul     /* 0.75MB emb bf16 [512,768] */
#define OFF_Q     42205184ul     /* 32MB Q bf16 */
#define OFF_K     75759616ul     /* 32MB K bf16 */
#define OFF_VT    109314048ul    /* 32MB V^T bf16 [16][1024(D)][1024(S)] */
#define OFF_RP    142868480ul    /* 1MB  Rp bf16 [512,1024] */
#define OFF_BOOST 143917056ul    /* 64KB boost fp32 [16384] */
#define OFF_BIG   143982592ul    /* 64MB: punt fp32 -> scores fp32 -> xboost fp32 */

extern "C" void kernel_launch(void* const* d_in, const int* in_sizes, int n_in,
                              void* d_out, int out_size, void* d_ws, size_t ws_size,
                              hipStream_t stream) {
    (void)in_sizes; (void)n_in; (void)ws_size;
    const float* lstm  = (const float*)d_in[0];
    const float* emb   = (const float*)d_in[1];
    const float* Wq    = (const float*)d_in[2];
    const float* bq    = (const float*)d_in[3];
    const float* Wk    = (const float*)d_in[4];
    const float* bk    = (const float*)d_in[5];
    const float* Wv    = (const float*)d_in[6];
    const float* bv    = (const float*)d_in[7];
    const float* Wpr   = (const float*)d_in[8];
    const float* bpr   = (const float*)d_in[9];
    const float* esc   = (const float*)d_in[10];
    const float* gamma = (const float*)d_in[11];
    const float* beta  = (const float*)d_in[12];
    float* out = (float*)d_out;

    char* ws = (char*)d_ws;
    ushort* Xbf  = (ushort*)(ws + OFF_XBF);
    ushort* Wqt  = (ushort*)(ws + OFF_WQT);
    ushort* Wkt  = (ushort*)(ws + OFF_WKT);
    ushort* Wvt  = (ushort*)(ws + OFF_WVT);
    ushort* Wprt = (ushort*)(ws + OFF_WPRT);
    ushort* Embb = (ushort*)(ws + OFF_EMBB);
    ushort* Qb   = (ushort*)(ws + OFF_Q);
    ushort* Kb   = (ushort*)(ws + OFF_K);
    ushort* Vt   = (ushort*)(ws + OFF_VT);
    ushort* Rp   = (ushort*)(ws + OFF_RP);
    float*  boost= (float*)(ws + OFF_BOOST);
    float*  big  = (float*)(ws + OFF_BIG);
    ushort* P    = (ushort*)(ws + OFF_XBF);   // alias: X no longer needed by then

    hipMemsetAsync(d_out, 0, (size_t)out_size * sizeof(float), stream);

    // casts
    {
        long n4 = (long)BB * SS * DD / 4;
        cast_f32_bf16<<<dim3((n4 + 255) / 256), dim3(256), 0, stream>>>(lstm, Xbf, n4);
        long e4 = (long)RR * EE / 4;
        cast_f32_bf16<<<dim3((e4 + 255) / 256), dim3(256), 0, stream>>>(emb, Embb, e4);
        transpose_cast<<<dim3(32, 32), dim3(32, 8), 0, stream>>>(Wq, Wqt, 1024, 1024);
        transpose_cast<<<dim3(32, 32), dim3(32, 8), 0, stream>>>(Wk, Wkt, 1024, 1024);
        transpose_cast<<<dim3(32, 32), dim3(32, 8), 0, stream>>>(Wv, Wvt, 1024, 1024);
        transpose_cast<<<dim3(32, 24), dim3(32, 8), 0, stream>>>(Wpr, Wprt, 768, 1024);
    }

    // Rp = emb @ Wpr + bpr   [512,1024] bf16
    gemm_bt<1, true, false><<<dim3(8, 4, 1), 256, 0, stream>>>(
        Embb, Wprt, Rp, bpr, nullptr, nullptr, 1024, 768, 512, 0, 0, 0);
    // Q = X @ Wq + bq   [16384,1024] bf16
    gemm_bt<1, true, false><<<dim3(8, 128, 1), 256, 0, stream>>>(
        Xbf, Wqt, Qb, bq, nullptr, nullptr, 1024, 1024, 16384, 0, 0, 0);
    // K = X @ Wk + bk
    gemm_bt<1, true, false><<<dim3(8, 128, 1), 256, 0, stream>>>(
        Xbf, Wkt, Kb, bk, nullptr, nullptr, 1024, 1024, 16384, 0, 0, 0);
    // Vt[b] = (X_b @ Wv)^T + bv (per-row bias)  [16][D][S]
    gemm_bt<2, true, false><<<dim3(8, 8, 16), 256, 0, stream>>>(
        Wvt, Xbf, Vt, bv, nullptr, nullptr, 1024, 1024, 1024,
        0, (long)SS * DD, (long)DD * SS);
    // punt = Q @ Rp^T  [16384,512] fp32 (in BIG)
    gemm_bt<0, false, false><<<dim3(4, 128, 1), 256, 0, stream>>>(
        Qb, Rp, big, nullptr, nullptr, nullptr, 512, 1024, 16384, 0, 0, 0);
    // boost = 1 + sigmoid(rowmax(punt))
    rowmax_boost<<<dim3(16384), 256, 0, stream>>>(big, boost);
    // scores[b] = Q_b @ K_b^T * escala  [16][1024][1024] fp32 (in BIG)
    gemm_bt<0, false, false><<<dim3(8, 8, 16), 256, 0, stream>>>(
        Qb, Kb, big, nullptr, nullptr, esc, 1024, 1024, 1024,
        (long)SS * DD, (long)SS * DD, (long)SS * SS);
    // P = softmax(scores) bf16 (into Xbf region)
    softmax_rows<<<dim3(16384), 256, 0, stream>>>(big, P);
    // xboost[b] = (P_b @ V_b) * boost  fp32 (in BIG, overwrites scores)
    gemm_bt<0, false, true><<<dim3(8, 8, 16), 256, 0, stream>>>(
        P, Vt, big, nullptr, boost, nullptr, 1024, 1024, 1024,
        (long)SS * SS, (long)DD * SS, (long)SS * DD);
    // LN + mean pool
    ln_pool<<<dim3(16, 16), 256, 0, stream>>>(big, gamma, beta, out);
}

// Round 4
// 459.721 us; speedup vs baseline: 1.2626x; 1.2626x over previous
//
#include <hip/hip_runtime.h>

// ---------------------------------------------------------------------------
// RiskAttention: q/k/v proj -> lexicon relevance -> self-attn -> boost -> LN -> pool
// B=16 S=1024 D=1024 R=512 E=768, fp32 in/out, bf16 MFMA compute.
// Round 1: 256x256 8-phase GEMM (T2 swizzle + T3/T4 counted vmcnt + T5 setprio
//          + XCD swizzle), glue kernels unchanged.
// Rounds 2-3: resubmit (bench infra timeouts — no result).
// ---------------------------------------------------------------------------

#define BB 16
#define SS 1024
#define DD 1024
#define RR 512
#define EE 768

typedef __attribute__((ext_vector_type(4))) float f32x4;
typedef __attribute__((ext_vector_type(8))) __bf16 bf16x8;

typedef __attribute__((address_space(1))) const void g_void;
typedef __attribute__((address_space(3))) void l_void;

__device__ __forceinline__ ushort f2b(float x) {
    unsigned u = __float_as_uint(x);
    u += 0x7fffu + ((u >> 16) & 1u);   // RNE
    return (ushort)(u >> 16);
}

// ---------------------------------------------------------------------------
// Casts
// ---------------------------------------------------------------------------
__global__ void cast_f32_bf16(const float* __restrict__ in, ushort* __restrict__ out, long n4) {
    long i = (long)blockIdx.x * blockDim.x + threadIdx.x;
    if (i >= n4) return;
    float4 v = *(const float4*)(in + i * 4);
    ushort4 o;
    o.x = f2b(v.x); o.y = f2b(v.y); o.z = f2b(v.z); o.w = f2b(v.w);
    *(ushort4*)(out + i * 4) = o;
}

// in [rows, cols] fp32 -> out [cols, rows] bf16
__global__ void transpose_cast(const float* __restrict__ in, ushort* __restrict__ out,
                               int rows, int cols) {
    __shared__ float tile[32][33];
    const int bx = blockIdx.x * 32;   // col base
    const int by = blockIdx.y * 32;   // row base
    const int tx = threadIdx.x;       // 0..31
    const int ty = threadIdx.y;       // 0..7
#pragma unroll
    for (int i = 0; i < 32; i += 8)
        tile[ty + i][tx] = in[(long)(by + ty + i) * cols + bx + tx];
    __syncthreads();
#pragma unroll
    for (int i = 0; i < 32; i += 8)
        out[(long)(bx + ty + i) * rows + by + tx] = f2b(tile[tx][ty + i]);
}

// ---------------------------------------------------------------------------
// 8-phase 256x256 BT-GEMM: C[z][m][n] = sum_k A[z][m][k]*B[z][n][k] (bf16 row-major)
// 8 waves (2Mx4N), BK=64, 2-deep LDS dbuf, XOR-swizzled LDS, counted vmcnt.
// ---------------------------------------------------------------------------

#define VMWAIT(N) asm volatile("s_waitcnt vmcnt(" #N ")" ::: "memory")
#define BARRIER() asm volatile("s_barrier" ::: "memory")

// Stage half-tile (mat: 0=A,1=B; mh: 0/1) of K-tile ti_ into LDS buffer buf.
// Linear LDS dest (wave-uniform base + lane*16B); swizzle applied on the
// per-lane GLOBAL source column: c = ((lane&7)^(lane>>3))*8.
#define STAGE(buf, mat, mh, ti_) do {                                              \
    const int ti__ = (ti_) < (T - 1) ? (ti_) : (T - 1);                            \
    const ushort* sp__ = (mat) ? Bb : Ab;                                          \
    const long kb__ = (long)ti__ * 64 + scol;                                      \
    _Pragma("unroll")                                                              \
    for (int i__ = 0; i__ < 2; ++i__) {                                            \
        const int row0__ = i__ * 128 + (mh) * 64 + wave * 8;                       \
        __builtin_amdgcn_global_load_lds(                                          \
            (g_void*)(sp__ + (long)(row0__ + srow) * K + kb__),                    \
            (l_void*)(&lds[(buf) * 2 + (mat)][row0__ * 64]), 16, 0, 0);            \
    }                                                                              \
} while (0)

// One phase: quadrant (mh, nh) of this wave's 128x64 C-tile, full BK=64.
// A-frags are read at nh==0 and reused at nh==1.
#define PHASE(cur_, mh, nh, STAGE_STMT, WAIT_STMT) do {                            \
    const int xo__ = (lane & 7) << 3;                                              \
    const int k0__ = (lane >> 4) * 8;                                              \
    if ((nh) == 0) {                                                               \
        _Pragma("unroll")                                                          \
        for (int mi = 0; mi < 4; ++mi) {                                           \
            const int row = wm * 128 + (mh) * 64 + mi * 16 + (lane & 15);          \
            af[mi][0] = *(const bf16x8*)&lds[(cur_) * 2 + 0][row * 64 + (k0__ ^ xo__)];        \
            af[mi][1] = *(const bf16x8*)&lds[(cur_) * 2 + 0][row * 64 + ((32 + k0__) ^ xo__)]; \
        }                                                                          \
    }                                                                              \
    _Pragma("unroll")                                                              \
    for (int ni = 0; ni < 2; ++ni) {                                               \
        const int row = wn * 64 + (nh) * 32 + ni * 16 + (lane & 15);               \
        bfr[ni][0] = *(const bf16x8*)&lds[(cur_) * 2 + 1][row * 64 + (k0__ ^ xo__)];        \
        bfr[ni][1] = *(const bf16x8*)&lds[(cur_) * 2 + 1][row * 64 + ((32 + k0__) ^ xo__)]; \
    }                                                                              \
    STAGE_STMT;                                                                    \
    BARRIER();                                                                     \
    __builtin_amdgcn_s_setprio(1);                                                 \
    _Pragma("unroll")                                                              \
    for (int mi = 0; mi < 4; ++mi)                                                 \
        _Pragma("unroll")                                                          \
        for (int ni = 0; ni < 2; ++ni) {                                           \
            acc[(mh) * 4 + mi][(nh) * 2 + ni] = __builtin_amdgcn_mfma_f32_16x16x32_bf16( \
                af[mi][0], bfr[ni][0], acc[(mh) * 4 + mi][(nh) * 2 + ni], 0, 0, 0);      \
            acc[(mh) * 4 + mi][(nh) * 2 + ni] = __builtin_amdgcn_mfma_f32_16x16x32_bf16( \
                af[mi][1], bfr[ni][1], acc[(mh) * 4 + mi][(nh) * 2 + ni], 0, 0, 0);      \
        }                                                                          \
    __builtin_amdgcn_s_setprio(0);                                                 \
    WAIT_STMT;                                                                     \
    BARRIER();                                                                     \
} while (0)

template <int BIAS_MODE, bool OUT_BF16, bool ROWSCALE>
__global__ __launch_bounds__(512, 2) void gemm8(
    const ushort* __restrict__ A, const ushort* __restrict__ B, void* __restrict__ C,
    const float* __restrict__ bias, const float* __restrict__ rowscale,
    const float* __restrict__ scale_ptr,
    int N, int K, int M, long sA, long sB, long sC)
{
    __shared__ ushort lds[4][16384];   // [buf*2 + mat][256 rows * 64 k] = 128 KiB
    const int tid  = threadIdx.x;
    const int wave = tid >> 6;
    const int lane = tid & 63;
    const int wm = wave >> 2, wn = wave & 3;      // 2 x 4 wave grid

    // XCD-chunked bijective block swizzle (all launches have nwg % 8 == 0)
    const int nx = gridDim.x, ny = gridDim.y;
    long flat = blockIdx.x + (long)nx * (blockIdx.y + (long)ny * blockIdx.z);
    const long nwg = (long)nx * ny * gridDim.z;
    const long cpx = nwg >> 3;
    flat = (flat & 7) * cpx + (flat >> 3);
    const int bn = (int)(flat % nx);
    const long r1 = flat / nx;
    const int bm = (int)(r1 % ny);
    const int bz = (int)(r1 / ny);

    const ushort* Ab = A + (long)bz * sA + (long)bm * 256 * K;
    const ushort* Bb = B + (long)bz * sB + (long)bn * 256 * K;
    const int T = K >> 6;

    const int srow = lane >> 3;                    // row within 8-row wave chunk
    const int scol = ((lane & 7) ^ srow) * 8;      // pre-swizzled source column

    f32x4 acc[8][4];
#pragma unroll
    for (int i = 0; i < 8; ++i)
#pragma unroll
        for (int j = 0; j < 4; ++j) acc[i][j] = (f32x4){0.f, 0.f, 0.f, 0.f};

    bf16x8 af[4][2], bfr[2][2];

    // Prologue: tile0 all 4 halves + tile1 Ah0/Bh0  (6 halves = 12 loads/wave)
    STAGE(0, 0, 0, 0); STAGE(0, 1, 0, 0); STAGE(0, 0, 1, 0); STAGE(0, 1, 1, 0);
    STAGE(1, 0, 0, 1); STAGE(1, 1, 0, 1);
    VMWAIT(8);          // oldest 4 loads (tile0 Ah0,Bh0) landed
    BARRIER();

    for (int t = 0; t < T; ++t) {
        const int cur = t & 1, nxt = cur ^ 1;
        // phase 0: quadrant (0,0); stage Ah1(t+1) -> nxt; wait guards Bh1(t)+Ah1(t)
        PHASE(cur, 0, 0, STAGE(nxt, 0, 1, t + 1), VMWAIT(6));
        // phase 1: quadrant (0,1); stage Bh1(t+1) -> nxt
        PHASE(cur, 0, 1, STAGE(nxt, 1, 1, t + 1), (void)0);
        // phase 2: quadrant (1,0); stage Ah0(t+2) -> cur (Ah0 dead since phase 0)
        PHASE(cur, 1, 0, STAGE(cur, 0, 0, t + 2), (void)0);
        // phase 3: quadrant (1,1); stage Bh0(t+2) -> cur; wait guards next Ah0/Bh0
        PHASE(cur, 1, 1, STAGE(cur, 1, 0, t + 2), VMWAIT(8));
    }
    VMWAIT(0);   // drain dummy stages before LDS goes out of scope

    // Epilogue: C/D mapping col=lane&15, row=(lane>>4)*4+j (verified round 0)
    const float scale = scale_ptr ? *scale_ptr : 1.0f;
    const int r  = lane & 15;
    const int g4 = (lane >> 4) * 4;
#pragma unroll
    for (int mi = 0; mi < 8; ++mi) {
        const int row0 = bm * 256 + wm * 128 + mi * 16 + g4;
#pragma unroll
        for (int ni = 0; ni < 4; ++ni) {
            const int col = bn * 256 + wn * 64 + ni * 16 + r;
            float bcol = (BIAS_MODE == 1) ? bias[col] : 0.0f;
#pragma unroll
            for (int j = 0; j < 4; ++j) {
                float v = acc[mi][ni][j] * scale;
                if (BIAS_MODE == 1) v += bcol;
                if (BIAS_MODE == 2) v += bias[row0 + j];
                if (ROWSCALE)       v *= rowscale[(long)bz * M + row0 + j];
                const long idx = (long)bz * sC + (long)(row0 + j) * N + col;
                if (OUT_BF16) ((ushort*)C)[idx] = f2b(v);
                else          ((float*)C)[idx]  = v;
            }
        }
    }
}

// ---------------------------------------------------------------------------
// rowmax over 512 + sigmoid -> boost = 1 + sigmoid(max)
// ---------------------------------------------------------------------------
__global__ void rowmax_boost(const float* __restrict__ punt, float* __restrict__ boost) {
    const long row = blockIdx.x;
    const int tid = threadIdx.x;
    __shared__ float sm[4];
    float m = fmaxf(punt[row * RR + tid], punt[row * RR + tid + 256]);
#pragma unroll
    for (int o = 32; o > 0; o >>= 1) m = fmaxf(m, __shfl_down(m, o));
    if ((tid & 63) == 0) sm[tid >> 6] = m;
    __syncthreads();
    if (tid == 0) {
        m = fmaxf(fmaxf(sm[0], sm[1]), fmaxf(sm[2], sm[3]));
        boost[row] = 1.0f + 1.0f / (1.0f + __expf(-m));
    }
}

// ---------------------------------------------------------------------------
// Row softmax: fp32 [rows,1024] -> bf16 [rows,1024]
// ---------------------------------------------------------------------------
__global__ void softmax_rows(const float* __restrict__ S, ushort* __restrict__ P) {
    const long row = blockIdx.x;
    const int tid = threadIdx.x;
    __shared__ float sm[4];
    float4 x = *(const float4*)(S + row * 1024 + tid * 4);
    float m = fmaxf(fmaxf(x.x, x.y), fmaxf(x.z, x.w));
#pragma unroll
    for (int o = 32; o > 0; o >>= 1) m = fmaxf(m, __shfl_down(m, o));
    if ((tid & 63) == 0) sm[tid >> 6] = m;
    __syncthreads();
    m = fmaxf(fmaxf(sm[0], sm[1]), fmaxf(sm[2], sm[3]));
    __syncthreads();
    float e0 = __expf(x.x - m), e1 = __expf(x.y - m);
    float e2 = __expf(x.z - m), e3 = __expf(x.w - m);
    float s = e0 + e1 + e2 + e3;
#pragma unroll
    for (int o = 32; o > 0; o >>= 1) s += __shfl_down(s, o);
    if ((tid & 63) == 0) sm[tid >> 6] = s;
    __syncthreads();
    s = sm[0] + sm[1] + sm[2] + sm[3];
    const float inv = 1.0f / s;
    ushort4 o4;
    o4.x = f2b(e0 * inv); o4.y = f2b(e1 * inv);
    o4.z = f2b(e2 * inv); o4.w = f2b(e3 * inv);
    *(ushort4*)(P + row * 1024 + tid * 4) = o4;
}

// ---------------------------------------------------------------------------
// LayerNorm over D + mean-pool over S (atomicAdd into out[b][d])
// ---------------------------------------------------------------------------
__global__ void ln_pool(const float* __restrict__ x, const float* __restrict__ gamma,
                        const float* __restrict__ beta, float* __restrict__ out) {
    const int b = blockIdx.y, chunk = blockIdx.x, tid = threadIdx.x;
    __shared__ float sm[8];
    float4 g  = *(const float4*)(gamma + tid * 4);
    float4 be = *(const float4*)(beta + tid * 4);
    float a0 = 0, a1 = 0, a2 = 0, a3 = 0;
    for (int s = chunk * 64; s < chunk * 64 + 64; ++s) {
        float4 xv = *(const float4*)(x + ((long)b * SS + s) * DD + tid * 4);
        float ls = xv.x + xv.y + xv.z + xv.w;
        float lq = xv.x * xv.x + xv.y * xv.y + xv.z * xv.z + xv.w * xv.w;
#pragma unroll
        for (int o = 32; o > 0; o >>= 1) { ls += __shfl_down(ls, o); lq += __shfl_down(lq, o); }
        if ((tid & 63) == 0) { sm[(tid >> 6) * 2] = ls; sm[(tid >> 6) * 2 + 1] = lq; }
        __syncthreads();
        const float ts = sm[0] + sm[2] + sm[4] + sm[6];
        const float tq = sm[1] + sm[3] + sm[5] + sm[7];
        __syncthreads();
        const float mu  = ts * (1.0f / DD);
        const float var = tq * (1.0f / DD) - mu * mu;
        const float rs  = rsqrtf(var + 1e-5f);
        a0 += (xv.x - mu) * rs * g.x + be.x;
        a1 += (xv.y - mu) * rs * g.y + be.y;
        a2 += (xv.z - mu) * rs * g.z + be.z;
        a3 += (xv.w - mu) * rs * g.w + be.w;
    }
    const float is = 1.0f / SS;
    atomicAdd(out + (long)b * DD + tid * 4 + 0, a0 * is);
    atomicAdd(out + (long)b * DD + tid * 4 + 1, a1 * is);
    atomicAdd(out + (long)b * DD + tid * 4 + 2, a2 * is);
    atomicAdd(out + (long)b * DD + tid * 4 + 3, a3 * is);
}

// ---------------------------------------------------------------------------
// Workspace layout (bytes)
// ---------------------------------------------------------------------------
#define OFF_XBF   0ul            /* 32MB bf16 X [16384,1024]; later reused for P */
#define OFF_WQT   33554432ul     /* 2MB  Wq^T [1024,1024] */
#define OFF_WKT   35651584ul
#define OFF_WVT   37748736ul
#define OFF_WPRT  39845888ul     /* 1.5MB Wpr^T [1024,768] */
#define OFF_EMBB  41418752ul     /* 0.75MB emb bf16 [512,768] */
#define OFF_Q     42205184ul     /* 32MB Q bf16 */
#define OFF_K     75759616ul     /* 32MB K bf16 */
#define OFF_VT    109314048ul    /* 32MB V^T bf16 [16][1024(D)][1024(S)] */
#define OFF_RP    142868480ul    /* 1MB  Rp bf16 [512,1024] */
#define OFF_BOOST 143917056ul    /* 64KB boost fp32 [16384] */
#define OFF_BIG   143982592ul    /* 64MB: punt fp32 -> scores fp32 -> xboost fp32 */

extern "C" void kernel_launch(void* const* d_in, const int* in_sizes, int n_in,
                              void* d_out, int out_size, void* d_ws, size_t ws_size,
                              hipStream_t stream) {
    (void)in_sizes; (void)n_in; (void)ws_size;
    const float* lstm  = (const float*)d_in[0];
    const float* emb   = (const float*)d_in[1];
    const float* Wq    = (const float*)d_in[2];
    const float* bq    = (const float*)d_in[3];
    const float* Wk    = (const float*)d_in[4];
    const float* bk    = (const float*)d_in[5];
    const float* Wv    = (const float*)d_in[6];
    const float* bv    = (const float*)d_in[7];
    const float* Wpr   = (const float*)d_in[8];
    const float* bpr   = (const float*)d_in[9];
    const float* esc   = (const float*)d_in[10];
    const float* gamma = (const float*)d_in[11];
    const float* beta  = (const float*)d_in[12];
    float* out = (float*)d_out;

    char* ws = (char*)d_ws;
    ushort* Xbf  = (ushort*)(ws + OFF_XBF);
    ushort* Wqt  = (ushort*)(ws + OFF_WQT);
    ushort* Wkt  = (ushort*)(ws + OFF_WKT);
    ushort* Wvt  = (ushort*)(ws + OFF_WVT);
    ushort* Wprt = (ushort*)(ws + OFF_WPRT);
    ushort* Embb = (ushort*)(ws + OFF_EMBB);
    ushort* Qb   = (ushort*)(ws + OFF_Q);
    ushort* Kb   = (ushort*)(ws + OFF_K);
    ushort* Vt   = (ushort*)(ws + OFF_VT);
    ushort* Rp   = (ushort*)(ws + OFF_RP);
    float*  boost= (float*)(ws + OFF_BOOST);
    float*  big  = (float*)(ws + OFF_BIG);
    ushort* P    = (ushort*)(ws + OFF_XBF);   // alias: X no longer needed by then

    hipMemsetAsync(d_out, 0, (size_t)out_size * sizeof(float), stream);

    // casts
    {
        long n4 = (long)BB * SS * DD / 4;
        cast_f32_bf16<<<dim3((n4 + 255) / 256), dim3(256), 0, stream>>>(lstm, Xbf, n4);
        long e4 = (long)RR * EE / 4;
        cast_f32_bf16<<<dim3((e4 + 255) / 256), dim3(256), 0, stream>>>(emb, Embb, e4);
        transpose_cast<<<dim3(32, 32), dim3(32, 8), 0, stream>>>(Wq, Wqt, 1024, 1024);
        transpose_cast<<<dim3(32, 32), dim3(32, 8), 0, stream>>>(Wk, Wkt, 1024, 1024);
        transpose_cast<<<dim3(32, 32), dim3(32, 8), 0, stream>>>(Wv, Wvt, 1024, 1024);
        transpose_cast<<<dim3(32, 24), dim3(32, 8), 0, stream>>>(Wpr, Wprt, 768, 1024);
    }

    // Rp = emb @ Wpr + bpr   [512,1024] bf16
    gemm8<1, true, false><<<dim3(4, 2, 1), 512, 0, stream>>>(
        Embb, Wprt, Rp, bpr, nullptr, nullptr, 1024, 768, 512, 0, 0, 0);
    // Q = X @ Wq + bq   [16384,1024] bf16
    gemm8<1, true, false><<<dim3(4, 64, 1), 512, 0, stream>>>(
        Xbf, Wqt, Qb, bq, nullptr, nullptr, 1024, 1024, 16384, 0, 0, 0);
    // K = X @ Wk + bk
    gemm8<1, true, false><<<dim3(4, 64, 1), 512, 0, stream>>>(
        Xbf, Wkt, Kb, bk, nullptr, nullptr, 1024, 1024, 16384, 0, 0, 0);
    // Vt[b] = (X_b @ Wv)^T + bv (per-row bias)  [16][D][S]
    gemm8<2, true, false><<<dim3(4, 4, 16), 512, 0, stream>>>(
        Wvt, Xbf, Vt, bv, nullptr, nullptr, 1024, 1024, 1024,
        0, (long)SS * DD, (long)DD * SS);
    // punt = Q @ Rp^T  [16384,512] fp32 (in BIG)
    gemm8<0, false, false><<<dim3(2, 64, 1), 512, 0, stream>>>(
        Qb, Rp, big, nullptr, nullptr, nullptr, 512, 1024, 16384, 0, 0, 0);
    // boost = 1 + sigmoid(rowmax(punt))
    rowmax_boost<<<dim3(16384), 256, 0, stream>>>(big, boost);
    // scores[b] = Q_b @ K_b^T * escala  [16][1024][1024] fp32 (in BIG)
    gemm8<0, false, false><<<dim3(4, 4, 16), 512, 0, stream>>>(
        Qb, Kb, big, nullptr, nullptr, esc, 1024, 1024, 1024,
        (long)SS * DD, (long)SS * DD, (long)SS * SS);
    // P = softmax(scores) bf16 (into Xbf region)
    softmax_rows<<<dim3(16384), 256, 0, stream>>>(big, P);
    // xboost[b] = (P_b @ V_b) * boost  fp32 (in BIG, overwrites scores)
    gemm8<0, false, true><<<dim3(4, 4, 16), 512, 0, stream>>>(
        P, Vt, big, nullptr, boost, nullptr, 1024, 1024, 1024,
        (long)SS * SS, (long)DD * SS, (long)SS * DD);
    // LN + mean pool
    ln_pool<<<dim3(16, 16), 256, 0, stream>>>(big, gamma, beta, out);
}

// Round 6
// 458.883 us; speedup vs baseline: 1.2649x; 1.0018x over previous
//
#include <hip/hip_runtime.h>

// ---------------------------------------------------------------------------
// RiskAttention: q/k/v proj -> lexicon relevance -> self-attn -> boost -> LN -> pool
// B=16 S=1024 D=1024 R=512 E=768, fp32 in/out, bf16 MFMA compute.
// Round 1: 256x256 8-phase GEMM (T2 swizzle + counted vmcnt + setprio + XCD swz).
// Round 4: 605 TF/GEMM == 2-phase ceiling -> compiler inserts vmcnt(0) before
//   plain-C++ ds_reads; move fragment loads to inline-asm ds_read_b128.
// Round 5 FAIL: second k-half encoded as +64B immediate; swizzled column is
//   (k0^xo)^32 (XOR), not +32 -> lanes with (lane&7)>=4 read the next row.
// Round 6: dual base regs per matrix (col0, col0^64B); offsets = row deltas only.
// ---------------------------------------------------------------------------

#define BB 16
#define SS 1024
#define DD 1024
#define RR 512
#define EE 768

typedef __attribute__((ext_vector_type(4))) float f32x4;
typedef __attribute__((ext_vector_type(8))) __bf16 bf16x8;
typedef __attribute__((ext_vector_type(4))) unsigned int u32x4;

typedef __attribute__((address_space(1))) const void g_void;
typedef __attribute__((address_space(3))) void l_void;

__device__ __forceinline__ ushort f2b(float x) {
    unsigned u = __float_as_uint(x);
    u += 0x7fffu + ((u >> 16) & 1u);   // RNE
    return (ushort)(u >> 16);
}

// ---------------------------------------------------------------------------
// Casts
// ---------------------------------------------------------------------------
__global__ void cast_f32_bf16(const float* __restrict__ in, ushort* __restrict__ out, long n4) {
    long i = (long)blockIdx.x * blockDim.x + threadIdx.x;
    if (i >= n4) return;
    float4 v = *(const float4*)(in + i * 4);
    ushort4 o;
    o.x = f2b(v.x); o.y = f2b(v.y); o.z = f2b(v.z); o.w = f2b(v.w);
    *(ushort4*)(out + i * 4) = o;
}

// in [rows, cols] fp32 -> out [cols, rows] bf16
__global__ void transpose_cast(const float* __restrict__ in, ushort* __restrict__ out,
                               int rows, int cols) {
    __shared__ float tile[32][33];
    const int bx = blockIdx.x * 32;   // col base
    const int by = blockIdx.y * 32;   // row base
    const int tx = threadIdx.x;       // 0..31
    const int ty = threadIdx.y;       // 0..7
#pragma unroll
    for (int i = 0; i < 32; i += 8)
        tile[ty + i][tx] = in[(long)(by + ty + i) * cols + bx + tx];
    __syncthreads();
#pragma unroll
    for (int i = 0; i < 32; i += 8)
        out[(long)(bx + ty + i) * rows + by + tx] = f2b(tile[tx][ty + i]);
}

// ---------------------------------------------------------------------------
// 8-phase 256x256 BT-GEMM: C[z][m][n] = sum_k A[z][m][k]*B[z][n][k] (bf16 row-major)
// 8 waves (2Mx4N), BK=64, 2-deep LDS dbuf, XOR-swizzled LDS, counted vmcnt,
// inline-asm ds_read_b128 fragment loads (legalizer cannot insert vmcnt drains).
// ---------------------------------------------------------------------------

#define VMWAIT(N) asm volatile("s_waitcnt vmcnt(" #N ")" ::: "memory")
#define BARRIER() asm volatile("s_barrier" ::: "memory")
#define LGKM0()   asm volatile("s_waitcnt lgkmcnt(0)" ::: "memory")
#define DSR(dst, addr, imm) \
    asm volatile("ds_read_b128 %0, %1 offset:" #imm : "=v"(dst) : "v"(addr))

// Stage half-tile (mat: 0=A,1=B; h: 0/1) of K-tile ti_ into LDS buffer buf.
// Linear LDS dest (wave-uniform base + lane*16B); swizzle applied on the
// per-lane GLOBAL source column: c = ((lane&7)^(lane>>3))*8.
// A-half h rows: {i*128 + h*64 + wave*8 + srow}                (= A phase reads)
// B-half h rows: {(i*2+(wave>>2))*64 + h*32 + (wave&3)*8 + srow} (= B phase reads)
#define STAGE(buf, mat, h, ti_) do {                                               \
    const int ti__ = (ti_) < (T - 1) ? (ti_) : (T - 1);                            \
    const ushort* sp__ = (mat) ? Bb : Ab;                                          \
    const long kb__ = (long)ti__ * 64 + scol;                                      \
    _Pragma("unroll")                                                              \
    for (int i__ = 0; i__ < 2; ++i__) {                                            \
        const int row0__ = (mat)                                                   \
            ? ((i__ * 2 + (wave >> 2)) * 64 + (h) * 32 + (wave & 3) * 8)           \
            : (i__ * 128 + (h) * 64 + wave * 8);                                   \
        __builtin_amdgcn_global_load_lds(                                          \
            (g_void*)(sp__ + (long)(row0__ + srow) * K + kb__),                    \
            (l_void*)(&lds[(buf) * 2 + (mat)][row0__ * 64]), 16, 0, 0);            \
    }                                                                              \
} while (0)

// One phase: quadrant (mh, nh) of this wave's 128x64 C-tile, full BK=64.
// A-frags read at nh==0, reused at nh==1. Reads issued pre-barrier (latency
// overlaps barrier); lgkmcnt(0)+sched_barrier(0) post-barrier per rule #18.
// Two bases per matrix: k-half 0 at col (k0^xo), k-half 1 at col (k0^xo)^32
// elements (XOR 64 bytes) -- immediates carry only row deltas.
#define PHASE(curoff_, mh, nh, STAGE_STMT, WAIT_STMT) do {                         \
    if ((nh) == 0) {                                                               \
        const unsigned a0__ = abase0 + (curoff_) + (mh) * 8192;                    \
        const unsigned a1__ = abase1 + (curoff_) + (mh) * 8192;                    \
        DSR(af[0][0], a0__, 0);    DSR(af[0][1], a1__, 0);                         \
        DSR(af[1][0], a0__, 2048); DSR(af[1][1], a1__, 2048);                      \
        DSR(af[2][0], a0__, 4096); DSR(af[2][1], a1__, 4096);                      \
        DSR(af[3][0], a0__, 6144); DSR(af[3][1], a1__, 6144);                      \
    }                                                                              \
    {                                                                              \
        const unsigned b0__ = bbase0 + (curoff_) + (nh) * 4096;                    \
        const unsigned b1__ = bbase1 + (curoff_) + (nh) * 4096;                    \
        DSR(bfr[0][0], b0__, 0);    DSR(bfr[0][1], b1__, 0);                       \
        DSR(bfr[1][0], b0__, 2048); DSR(bfr[1][1], b1__, 2048);                    \
    }                                                                              \
    STAGE_STMT;                                                                    \
    BARRIER();                                                                     \
    LGKM0();                                                                       \
    __builtin_amdgcn_sched_barrier(0);                                             \
    __builtin_amdgcn_s_setprio(1);                                                 \
    _Pragma("unroll")                                                              \
    for (int mi = 0; mi < 4; ++mi)                                                 \
        _Pragma("unroll")                                                          \
        for (int ni = 0; ni < 2; ++ni) {                                           \
            acc[(mh) * 4 + mi][(nh) * 2 + ni] = __builtin_amdgcn_mfma_f32_16x16x32_bf16( \
                __builtin_bit_cast(bf16x8, af[mi][0]),                             \
                __builtin_bit_cast(bf16x8, bfr[ni][0]),                            \
                acc[(mh) * 4 + mi][(nh) * 2 + ni], 0, 0, 0);                       \
            acc[(mh) * 4 + mi][(nh) * 2 + ni] = __builtin_amdgcn_mfma_f32_16x16x32_bf16( \
                __builtin_bit_cast(bf16x8, af[mi][1]),                             \
                __builtin_bit_cast(bf16x8, bfr[ni][1]),                            \
                acc[(mh) * 4 + mi][(nh) * 2 + ni], 0, 0, 0);                       \
        }                                                                          \
    __builtin_amdgcn_s_setprio(0);                                                 \
    WAIT_STMT;                                                                     \
    BARRIER();                                                                     \
} while (0)

template <int BIAS_MODE, bool OUT_BF16, bool ROWSCALE>
__global__ __launch_bounds__(512, 2) void gemm8(
    const ushort* __restrict__ A, const ushort* __restrict__ B, void* __restrict__ C,
    const float* __restrict__ bias, const float* __restrict__ rowscale,
    const float* __restrict__ scale_ptr,
    int N, int K, int M, long sA, long sB, long sC)
{
    __shared__ ushort lds[4][16384];   // [buf*2 + mat][256 rows * 64 k] = 128 KiB
    const int tid  = threadIdx.x;
    const int wave = tid >> 6;
    const int lane = tid & 63;
    const int wm = wave >> 2, wn = wave & 3;      // 2 x 4 wave grid

    // XCD-chunked bijective block swizzle (all launches have nwg % 8 == 0)
    const int nx = gridDim.x, ny = gridDim.y;
    long flat = blockIdx.x + (long)nx * (blockIdx.y + (long)ny * blockIdx.z);
    const long nwg = (long)nx * ny * gridDim.z;
    const long cpx = nwg >> 3;
    flat = (flat & 7) * cpx + (flat >> 3);
    const int bn = (int)(flat % nx);
    const long r1 = flat / nx;
    const int bm = (int)(r1 % ny);
    const int bz = (int)(r1 / ny);

    const ushort* Ab = A + (long)bz * sA + (long)bm * 256 * K;
    const ushort* Bb = B + (long)bz * sB + (long)bn * 256 * K;
    const int T = K >> 6;

    const int srow = lane >> 3;                    // row within 8-row wave chunk
    const int scol = ((lane & 7) ^ srow) * 8;      // pre-swizzled source column

    // LDS byte bases for fragment reads (low 32 bits of generic ptr = LDS offset)
    const unsigned lb = (unsigned)(unsigned long long)(void*)&lds[0][0];
    const int r15 = lane & 15;
    const int k0  = (lane >> 4) * 8;               // k-element offset of fragment
    const int xo  = (lane & 7) * 8;                // row-swizzle (row&7 == lane&7)
    const unsigned colA = (unsigned)((k0 ^ xo) * 2);          // k-half 0, bytes
    const unsigned arow = (unsigned)((wm * 128 + r15) * 128);
    const unsigned brow = (unsigned)((wn * 64 + r15) * 128);
    const unsigned abase0 = lb + arow + colA;
    const unsigned abase1 = lb + arow + (colA ^ 64u);         // k-half 1 (XOR!)
    const unsigned bbase0 = lb + 32768u + brow + colA;
    const unsigned bbase1 = lb + 32768u + brow + (colA ^ 64u);

    f32x4 acc[8][4];
#pragma unroll
    for (int i = 0; i < 8; ++i)
#pragma unroll
        for (int j = 0; j < 4; ++j) acc[i][j] = (f32x4){0.f, 0.f, 0.f, 0.f};

    u32x4 af[4][2], bfr[2][2];

    // Prologue: tile0 all 4 halves + tile1 Ah0/Bh0  (6 halves = 12 loads/wave)
    STAGE(0, 0, 0, 0); STAGE(0, 1, 0, 0); STAGE(0, 0, 1, 0); STAGE(0, 1, 1, 0);
    STAGE(1, 0, 0, 1); STAGE(1, 1, 0, 1);
    VMWAIT(8);          // oldest 4 loads (tile0 Ah0,Bh0) landed
    BARRIER();

    for (int t = 0; t < T; ++t) {
        const int cur = t & 1, nxt = cur ^ 1;
        const unsigned curoff = cur ? 65536u : 0u;
        // phase 0: quadrant (0,0); stage Ah1(t+1)->nxt; wait lands Ah1(t),Bh1(t)
        PHASE(curoff, 0, 0, STAGE(nxt, 0, 1, t + 1), VMWAIT(6));
        // phase 1: quadrant (0,1); stage Bh1(t+1)->nxt
        PHASE(curoff, 0, 1, STAGE(nxt, 1, 1, t + 1), (void)0);
        // phase 2: quadrant (1,0); stage Ah0(t+2)->cur (Ah0(t) dead since ph0)
        PHASE(curoff, 1, 0, STAGE(cur, 0, 0, t + 2), (void)0);
        // phase 3: quadrant (1,1); stage Bh0(t+2)->cur; wait lands Ah0/Bh0(t+1)
        PHASE(curoff, 1, 1, STAGE(cur, 1, 0, t + 2), VMWAIT(8));
    }
    VMWAIT(0);   // drain dummy stages before LDS goes out of scope

    // Epilogue: C/D mapping col=lane&15, row=(lane>>4)*4+j (verified round 0)
    const float scale = scale_ptr ? *scale_ptr : 1.0f;
    const int g4 = (lane >> 4) * 4;
#pragma unroll
    for (int mi = 0; mi < 8; ++mi) {
        const int row0 = bm * 256 + wm * 128 + mi * 16 + g4;
#pragma unroll
        for (int ni = 0; ni < 4; ++ni) {
            const int col = bn * 256 + wn * 64 + ni * 16 + r15;
            float bcol = (BIAS_MODE == 1) ? bias[col] : 0.0f;
#pragma unroll
            for (int j = 0; j < 4; ++j) {
                float v = acc[mi][ni][j] * scale;
                if (BIAS_MODE == 1) v += bcol;
                if (BIAS_MODE == 2) v += bias[row0 + j];
                if (ROWSCALE)       v *= rowscale[(long)bz * M + row0 + j];
                const long idx = (long)bz * sC + (long)(row0 + j) * N + col;
                if (OUT_BF16) ((ushort*)C)[idx] = f2b(v);
                else          ((float*)C)[idx]  = v;
            }
        }
    }
}

// ---------------------------------------------------------------------------
// rowmax over 512 + sigmoid -> boost = 1 + sigmoid(max)
// ---------------------------------------------------------------------------
__global__ void rowmax_boost(const float* __restrict__ punt, float* __restrict__ boost) {
    const long row = blockIdx.x;
    const int tid = threadIdx.x;
    __shared__ float sm[4];
    float m = fmaxf(punt[row * RR + tid], punt[row * RR + tid + 256]);
#pragma unroll
    for (int o = 32; o > 0; o >>= 1) m = fmaxf(m, __shfl_down(m, o));
    if ((tid & 63) == 0) sm[tid >> 6] = m;
    __syncthreads();
    if (tid == 0) {
        m = fmaxf(fmaxf(sm[0], sm[1]), fmaxf(sm[2], sm[3]));
        boost[row] = 1.0f + 1.0f / (1.0f + __expf(-m));
    }
}

// ---------------------------------------------------------------------------
// Row softmax: fp32 [rows,1024] -> bf16 [rows,1024]
// ---------------------------------------------------------------------------
__global__ void softmax_rows(const float* __restrict__ S, ushort* __restrict__ P) {
    const long row = blockIdx.x;
    const int tid = threadIdx.x;
    __shared__ float sm[4];
    float4 x = *(const float4*)(S + row * 1024 + tid * 4);
    float m = fmaxf(fmaxf(x.x, x.y), fmaxf(x.z, x.w));
#pragma unroll
    for (int o = 32; o > 0; o >>= 1) m = fmaxf(m, __shfl_down(m, o));
    if ((tid & 63) == 0) sm[tid >> 6] = m;
    __syncthreads();
    m = fmaxf(fmaxf(sm[0], sm[1]), fmaxf(sm[2], sm[3]));
    __syncthreads();
    float e0 = __expf(x.x - m), e1 = __expf(x.y - m);
    float e2 = __expf(x.z - m), e3 = __expf(x.w - m);
    float s = e0 + e1 + e2 + e3;
#pragma unroll
    for (int o = 32; o > 0; o >>= 1) s += __shfl_down(s, o);
    if ((tid & 63) == 0) sm[tid >> 6] = s;
    __syncthreads();
    s = sm[0] + sm[1] + sm[2] + sm[3];
    const float inv = 1.0f / s;
    ushort4 o4;
    o4.x = f2b(e0 * inv); o4.y = f2b(e1 * inv);
    o4.z = f2b(e2 * inv); o4.w = f2b(e3 * inv);
    *(ushort4*)(P + row * 1024 + tid * 4) = o4;
}

// ---------------------------------------------------------------------------
// LayerNorm over D + mean-pool over S (atomicAdd into out[b][d])
// ---------------------------------------------------------------------------
__global__ void ln_pool(const float* __restrict__ x, const float* __restrict__ gamma,
                        const float* __restrict__ beta, float* __restrict__ out) {
    const int b = blockIdx.y, chunk = blockIdx.x, tid = threadIdx.x;
    __shared__ float sm[8];
    float4 g  = *(const float4*)(gamma + tid * 4);
    float4 be = *(const float4*)(beta + tid * 4);
    float a0 = 0, a1 = 0, a2 = 0, a3 = 0;
    for (int s = chunk * 64; s < chunk * 64 + 64; ++s) {
        float4 xv = *(const float4*)(x + ((long)b * SS + s) * DD + tid * 4);
        float ls = xv.x + xv.y + xv.z + xv.w;
        float lq = xv.x * xv.x + xv.y * xv.y + xv.z * xv.z + xv.w * xv.w;
#pragma unroll
        for (int o = 32; o > 0; o >>= 1) { ls += __shfl_down(ls, o); lq += __shfl_down(lq, o); }
        if ((tid & 63) == 0) { sm[(tid >> 6) * 2] = ls; sm[(tid >> 6) * 2 + 1] = lq; }
        __syncthreads();
        const float ts = sm[0] + sm[2] + sm[4] + sm[6];
        const float tq = sm[1] + sm[3] + sm[5] + sm[7];
        __syncthreads();
        const float mu  = ts * (1.0f / DD);
        const float var = tq * (1.0f / DD) - mu * mu;
        const float rs  = rsqrtf(var + 1e-5f);
        a0 += (xv.x - mu) * rs * g.x + be.x;
        a1 += (xv.y - mu) * rs * g.y + be.y;
        a2 += (xv.z - mu) * rs * g.z + be.z;
        a3 += (xv.w - mu) * rs * g.w + be.w;
    }
    const float is = 1.0f / SS;
    atomicAdd(out + (long)b * DD + tid * 4 + 0, a0 * is);
    atomicAdd(out + (long)b * DD + tid * 4 + 1, a1 * is);
    atomicAdd(out + (long)b * DD + tid * 4 + 2, a2 * is);
    atomicAdd(out + (long)b * DD + tid * 4 + 3, a3 * is);
}

// ---------------------------------------------------------------------------
// Workspace layout (bytes)
// ---------------------------------------------------------------------------
#define OFF_XBF   0ul            /* 32MB bf16 X [16384,1024]; later reused for P */
#define OFF_WQT   33554432ul     /* 2MB  Wq^T [1024,1024] */
#define OFF_WKT   35651584ul
#define OFF_WVT   37748736ul
#define OFF_WPRT  39845888ul     /* 1.5MB Wpr^T [1024,768] */
#define OFF_EMBB  41418752ul     /* 0.75MB emb bf16 [512,768] */
#define OFF_Q     42205184ul     /* 32MB Q bf16 */
#define OFF_K     75759616ul     /* 32MB K bf16 */
#define OFF_VT    109314048ul    /* 32MB V^T bf16 [16][1024(D)][1024(S)] */
#define OFF_RP    142868480ul    /* 1MB  Rp bf16 [512,1024] */
#define OFF_BOOST 143917056ul    /* 64KB boost fp32 [16384] */
#define OFF_BIG   143982592ul    /* 64MB: punt fp32 -> scores fp32 -> xboost fp32 */

extern "C" void kernel_launch(void* const* d_in, const int* in_sizes, int n_in,
                              void* d_out, int out_size, void* d_ws, size_t ws_size,
                              hipStream_t stream) {
    (void)in_sizes; (void)n_in; (void)ws_size;
    const float* lstm  = (const float*)d_in[0];
    const float* emb   = (const float*)d_in[1];
    const float* Wq    = (const float*)d_in[2];
    const float* bq    = (const float*)d_in[3];
    const float* Wk    = (const float*)d_in[4];
    const float* bk    = (const float*)d_in[5];
    const float* Wv    = (const float*)d_in[6];
    const float* bv    = (const float*)d_in[7];
    const float* Wpr   = (const float*)d_in[8];
    const float* bpr   = (const float*)d_in[9];
    const float* esc   = (const float*)d_in[10];
    const float* gamma = (const float*)d_in[11];
    const float* beta  = (const float*)d_in[12];
    float* out = (float*)d_out;

    char* ws = (char*)d_ws;
    ushort* Xbf  = (ushort*)(ws + OFF_XBF);
    ushort* Wqt  = (ushort*)(ws + OFF_WQT);
    ushort* Wkt  = (ushort*)(ws + OFF_WKT);
    ushort* Wvt  = (ushort*)(ws + OFF_WVT);
    ushort* Wprt = (ushort*)(ws + OFF_WPRT);
    ushort* Embb = (ushort*)(ws + OFF_EMBB);
    ushort* Qb   = (ushort*)(ws + OFF_Q);
    ushort* Kb   = (ushort*)(ws + OFF_K);
    ushort* Vt   = (ushort*)(ws + OFF_VT);
    ushort* Rp   = (ushort*)(ws + OFF_RP);
    float*  boost= (float*)(ws + OFF_BOOST);
    float*  big  = (float*)(ws + OFF_BIG);
    ushort* P    = (ushort*)(ws + OFF_XBF);   // alias: X no longer needed by then

    hipMemsetAsync(d_out, 0, (size_t)out_size * sizeof(float), stream);

    // casts
    {
        long n4 = (long)BB * SS * DD / 4;
        cast_f32_bf16<<<dim3((n4 + 255) / 256), dim3(256), 0, stream>>>(lstm, Xbf, n4);
        long e4 = (long)RR * EE / 4;
        cast_f32_bf16<<<dim3((e4 + 255) / 256), dim3(256), 0, stream>>>(emb, Embb, e4);
        transpose_cast<<<dim3(32, 32), dim3(32, 8), 0, stream>>>(Wq, Wqt, 1024, 1024);
        transpose_cast<<<dim3(32, 32), dim3(32, 8), 0, stream>>>(Wk, Wkt, 1024, 1024);
        transpose_cast<<<dim3(32, 32), dim3(32, 8), 0, stream>>>(Wv, Wvt, 1024, 1024);
        transpose_cast<<<dim3(32, 24), dim3(32, 8), 0, stream>>>(Wpr, Wprt, 768, 1024);
    }

    // Rp = emb @ Wpr + bpr   [512,1024] bf16
    gemm8<1, true, false><<<dim3(4, 2, 1), 512, 0, stream>>>(
        Embb, Wprt, Rp, bpr, nullptr, nullptr, 1024, 768, 512, 0, 0, 0);
    // Q = X @ Wq + bq   [16384,1024] bf16
    gemm8<1, true, false><<<dim3(4, 64, 1), 512, 0, stream>>>(
        Xbf, Wqt, Qb, bq, nullptr, nullptr, 1024, 1024, 16384, 0, 0, 0);
    // K = X @ Wk + bk
    gemm8<1, true, false><<<dim3(4, 64, 1), 512, 0, stream>>>(
        Xbf, Wkt, Kb, bk, nullptr, nullptr, 1024, 1024, 16384, 0, 0, 0);
    // Vt[b] = (X_b @ Wv)^T + bv (per-row bias)  [16][D][S]
    gemm8<2, true, false><<<dim3(4, 4, 16), 512, 0, stream>>>(
        Wvt, Xbf, Vt, bv, nullptr, nullptr, 1024, 1024, 1024,
        0, (long)SS * DD, (long)DD * SS);
    // punt = Q @ Rp^T  [16384,512] fp32 (in BIG)
    gemm8<0, false, false><<<dim3(2, 64, 1), 512, 0, stream>>>(
        Qb, Rp, big, nullptr, nullptr, nullptr, 512, 1024, 16384, 0, 0, 0);
    // boost = 1 + sigmoid(rowmax(punt))
    rowmax_boost<<<dim3(16384), 256, 0, stream>>>(big, boost);
    // scores[b] = Q_b @ K_b^T * escala  [16][1024][1024] fp32 (in BIG)
    gemm8<0, false, false><<<dim3(4, 4, 16), 512, 0, stream>>>(
        Qb, Kb, big, nullptr, nullptr, esc, 1024, 1024, 1024,
        (long)SS * DD, (long)SS * DD, (long)SS * SS);
    // P = softmax(scores) bf16 (into Xbf region)
    softmax_rows<<<dim3(16384), 256, 0, stream>>>(big, P);
    // xboost[b] = (P_b @ V_b) * boost  fp32 (in BIG, overwrites scores)
    gemm8<0, false, true><<<dim3(4, 4, 16), 512, 0, stream>>>(
        P, Vt, big, nullptr, boost, nullptr, 1024, 1024, 1024,
        (long)SS * SS, (long)DD * SS, (long)SS * DD);
    // LN + mean pool
    ln_pool<<<dim3(16, 16), 256, 0, stream>>>(big, gamma, beta, out);
}

// Round 7
// 439.228 us; speedup vs baseline: 1.3215x; 1.0447x over previous
//
#include <hip/hip_runtime.h>

// ---------------------------------------------------------------------------
// RiskAttention: q/k/v proj -> lexicon relevance -> self-attn -> boost -> LN -> pool
// B=16 S=1024 D=1024 R=512 E=768, fp32 in/out, bf16 MFMA compute.
// Round 6: 8-phase 256^2 GEMM w/ asm ds_read (49us/GEMM, MfmaUtil 27%).
// Round 7: (a) phase order (0,0)(0,1)(1,1)(1,0) + dual-buffered B-frags:
//   LDS reads 32->24 per K-tile (B no longer re-read per mh). Waits re-derived:
//   VMWAIT(6) @ph0-end lands Bh1(t)/Ah1(t); VMWAIT(8) @ph3-end lands Ah0/Bh0(t+1).
//   (b) bf16 intermediates (punt/scores/xboost): -150MB HBM traffic.
// ---------------------------------------------------------------------------

#define BB 16
#define SS 1024
#define DD 1024
#define RR 512
#define EE 768

typedef __attribute__((ext_vector_type(4))) float f32x4;
typedef __attribute__((ext_vector_type(8))) __bf16 bf16x8;
typedef __attribute__((ext_vector_type(4))) unsigned int u32x4;

typedef __attribute__((address_space(1))) const void g_void;
typedef __attribute__((address_space(3))) void l_void;

__device__ __forceinline__ ushort f2b(float x) {
    unsigned u = __float_as_uint(x);
    u += 0x7fffu + ((u >> 16) & 1u);   // RNE
    return (ushort)(u >> 16);
}
__device__ __forceinline__ float b2f(ushort u) {
    return __uint_as_float((unsigned)u << 16);
}

// ---------------------------------------------------------------------------
// Casts
// ---------------------------------------------------------------------------
__global__ void cast_f32_bf16(const float* __restrict__ in, ushort* __restrict__ out, long n4) {
    long i = (long)blockIdx.x * blockDim.x + threadIdx.x;
    if (i >= n4) return;
    float4 v = *(const float4*)(in + i * 4);
    ushort4 o;
    o.x = f2b(v.x); o.y = f2b(v.y); o.z = f2b(v.z); o.w = f2b(v.w);
    *(ushort4*)(out + i * 4) = o;
}

// in [rows, cols] fp32 -> out [cols, rows] bf16
__global__ void transpose_cast(const float* __restrict__ in, ushort* __restrict__ out,
                               int rows, int cols) {
    __shared__ float tile[32][33];
    const int bx = blockIdx.x * 32;   // col base
    const int by = blockIdx.y * 32;   // row base
    const int tx = threadIdx.x;       // 0..31
    const int ty = threadIdx.y;       // 0..7
#pragma unroll
    for (int i = 0; i < 32; i += 8)
        tile[ty + i][tx] = in[(long)(by + ty + i) * cols + bx + tx];
    __syncthreads();
#pragma unroll
    for (int i = 0; i < 32; i += 8)
        out[(long)(bx + ty + i) * rows + by + tx] = f2b(tile[tx][ty + i]);
}

// ---------------------------------------------------------------------------
// 8-phase 256x256 BT-GEMM: C[z][m][n] = sum_k A[z][m][k]*B[z][n][k] (bf16 row-major)
// 8 waves (2Mx4N), BK=64, 2-deep LDS dbuf, XOR-swizzled LDS, counted vmcnt,
// inline-asm ds_read_b128 fragment loads. B-frags dual-buffered across nh.
// ---------------------------------------------------------------------------

#define VMWAIT(N) asm volatile("s_waitcnt vmcnt(" #N ")" ::: "memory")
#define BARRIER() asm volatile("s_barrier" ::: "memory")
#define LGKM0()   asm volatile("s_waitcnt lgkmcnt(0)" ::: "memory")
#define DSR(dst, addr, imm) \
    asm volatile("ds_read_b128 %0, %1 offset:" #imm : "=v"(dst) : "v"(addr))

// Stage half-tile (mat: 0=A,1=B; h: 0/1) of K-tile ti_ into LDS buffer buf.
// Linear LDS dest (wave-uniform base + lane*16B); swizzle applied on the
// per-lane GLOBAL source column: c = ((lane&7)^(lane>>3))*8.
// A-half h rows: {i*128 + h*64 + wave*8 + srow}                (= A phase reads)
// B-half h rows: {(i*2+(wave>>2))*64 + h*32 + (wave&3)*8 + srow} (= B phase reads)
#define STAGE(buf, mat, h, ti_) do {                                               \
    const int ti__ = (ti_) < (T - 1) ? (ti_) : (T - 1);                            \
    const ushort* sp__ = (mat) ? Bb : Ab;                                          \
    const long kb__ = (long)ti__ * 64 + scol;                                      \
    _Pragma("unroll")                                                              \
    for (int i__ = 0; i__ < 2; ++i__) {                                            \
        const int row0__ = (mat)                                                   \
            ? ((i__ * 2 + (wave >> 2)) * 64 + (h) * 32 + (wave & 3) * 8)           \
            : (i__ * 128 + (h) * 64 + wave * 8);                                   \
        __builtin_amdgcn_global_load_lds(                                          \
            (g_void*)(sp__ + (long)(row0__ + srow) * K + kb__),                    \
            (l_void*)(&lds[(buf) * 2 + (mat)][row0__ * 64]), 16, 0, 0);            \
    }                                                                              \
} while (0)

// One phase: quadrant (mh, nh). RA: read A-frags for mh (8 DSR, dead A reuse).
// RB: read B-frags for nh into bfr[nh] (4 DSR). LG: lgkmcnt(0)+sched_barrier
// fence (rule #18) -- only when this phase issued/consumes fresh ds_reads.
// Two bases per matrix: k-half 0 at col (k0^xo), k-half 1 at (k0^xo)^64B (XOR).
#define PHASE(curoff_, mh, nh, RA, RB, STAGE_STMT, WAIT_STMT, LG) do {             \
    if (RA) {                                                                      \
        const unsigned a0__ = abase0 + (curoff_) + (mh) * 8192;                    \
        const unsigned a1__ = abase1 + (curoff_) + (mh) * 8192;                    \
        DSR(af[0][0], a0__, 0);    DSR(af[0][1], a1__, 0);                         \
        DSR(af[1][0], a0__, 2048); DSR(af[1][1], a1__, 2048);                      \
        DSR(af[2][0], a0__, 4096); DSR(af[2][1], a1__, 4096);                      \
        DSR(af[3][0], a0__, 6144); DSR(af[3][1], a1__, 6144);                      \
    }                                                                              \
    if (RB) {                                                                      \
        const unsigned b0__ = bbase0 + (curoff_) + (nh) * 4096;                    \
        const unsigned b1__ = bbase1 + (curoff_) + (nh) * 4096;                    \
        DSR(bfr[nh][0][0], b0__, 0);    DSR(bfr[nh][0][1], b1__, 0);               \
        DSR(bfr[nh][1][0], b0__, 2048); DSR(bfr[nh][1][1], b1__, 2048);            \
    }                                                                              \
    STAGE_STMT;                                                                    \
    BARRIER();                                                                     \
    if (LG) { LGKM0(); __builtin_amdgcn_sched_barrier(0); }                        \
    __builtin_amdgcn_s_setprio(1);                                                 \
    _Pragma("unroll")                                                              \
    for (int mi = 0; mi < 4; ++mi)                                                 \
        _Pragma("unroll")                                                          \
        for (int ni = 0; ni < 2; ++ni) {                                           \
            acc[(mh) * 4 + mi][(nh) * 2 + ni] = __builtin_amdgcn_mfma_f32_16x16x32_bf16( \
                __builtin_bit_cast(bf16x8, af[mi][0]),                             \
                __builtin_bit_cast(bf16x8, bfr[nh][ni][0]),                        \
                acc[(mh) * 4 + mi][(nh) * 2 + ni], 0, 0, 0);                       \
            acc[(mh) * 4 + mi][(nh) * 2 + ni] = __builtin_amdgcn_mfma_f32_16x16x32_bf16( \
                __builtin_bit_cast(bf16x8, af[mi][1]),                             \
                __builtin_bit_cast(bf16x8, bfr[nh][ni][1]),                        \
                acc[(mh) * 4 + mi][(nh) * 2 + ni], 0, 0, 0);                       \
        }                                                                          \
    __builtin_amdgcn_s_setprio(0);                                                 \
    WAIT_STMT;                                                                     \
    BARRIER();                                                                     \
} while (0)

template <int BIAS_MODE, bool OUT_BF16, bool ROWSCALE>
__global__ __launch_bounds__(512, 2) void gemm8(
    const ushort* __restrict__ A, const ushort* __restrict__ B, void* __restrict__ C,
    const float* __restrict__ bias, const float* __restrict__ rowscale,
    const float* __restrict__ scale_ptr,
    int N, int K, int M, long sA, long sB, long sC)
{
    __shared__ ushort lds[4][16384];   // [buf*2 + mat][256 rows * 64 k] = 128 KiB
    const int tid  = threadIdx.x;
    const int wave = tid >> 6;
    const int lane = tid & 63;
    const int wm = wave >> 2, wn = wave & 3;      // 2 x 4 wave grid

    // XCD-chunked bijective block swizzle (all launches have nwg % 8 == 0)
    const int nx = gridDim.x, ny = gridDim.y;
    long flat = blockIdx.x + (long)nx * (blockIdx.y + (long)ny * blockIdx.z);
    const long nwg = (long)nx * ny * gridDim.z;
    const long cpx = nwg >> 3;
    flat = (flat & 7) * cpx + (flat >> 3);
    const int bn = (int)(flat % nx);
    const long r1 = flat / nx;
    const int bm = (int)(r1 % ny);
    const int bz = (int)(r1 / ny);

    const ushort* Ab = A + (long)bz * sA + (long)bm * 256 * K;
    const ushort* Bb = B + (long)bz * sB + (long)bn * 256 * K;
    const int T = K >> 6;

    const int srow = lane >> 3;                    // row within 8-row wave chunk
    const int scol = ((lane & 7) ^ srow) * 8;      // pre-swizzled source column

    // LDS byte bases for fragment reads (low 32 bits of generic ptr = LDS offset)
    const unsigned lb = (unsigned)(unsigned long long)(void*)&lds[0][0];
    const int r15 = lane & 15;
    const int k0  = (lane >> 4) * 8;               // k-element offset of fragment
    const int xo  = (lane & 7) * 8;                // row-swizzle (row&7 == lane&7)
    const unsigned colA = (unsigned)((k0 ^ xo) * 2);          // k-half 0, bytes
    const unsigned arow = (unsigned)((wm * 128 + r15) * 128);
    const unsigned brow = (unsigned)((wn * 64 + r15) * 128);
    const unsigned abase0 = lb + arow + colA;
    const unsigned abase1 = lb + arow + (colA ^ 64u);         // k-half 1 (XOR!)
    const unsigned bbase0 = lb + 32768u + brow + colA;
    const unsigned bbase1 = lb + 32768u + brow + (colA ^ 64u);

    f32x4 acc[8][4];
#pragma unroll
    for (int i = 0; i < 8; ++i)
#pragma unroll
        for (int j = 0; j < 4; ++j) acc[i][j] = (f32x4){0.f, 0.f, 0.f, 0.f};

    u32x4 af[4][2], bfr[2][2][2];   // af[mi][kh]; bfr[nh][ni][kh]

    // Prologue: tile0 {A0,B0,B1,A1} + tile1 {A0,B0}  (6 stages = 12 loads/wave)
    STAGE(0, 0, 0, 0); STAGE(0, 1, 0, 0); STAGE(0, 1, 1, 0); STAGE(0, 0, 1, 0);
    STAGE(1, 0, 0, 1); STAGE(1, 1, 0, 1);
    VMWAIT(8);          // oldest 2 stages (tile0 A0,B0) landed
    BARRIER();

    for (int t = 0; t < T; ++t) {
        const int cur = t & 1, nxt = cur ^ 1;
        const unsigned curoff = cur ? 65536u : 0u;
        // ph0 (0,0): read A0+B0; stage Ah1(t+1)->nxt; wait lands Bh1(t),Ah1(t)
        PHASE(curoff, 0, 0, 1, 1, STAGE(nxt, 0, 1, t + 1), VMWAIT(6), 1);
        // ph1 (0,1): read B1; stage Bh1(t+1)->nxt
        PHASE(curoff, 0, 1, 0, 1, STAGE(nxt, 1, 1, t + 1), (void)0, 1);
        // ph2 (1,1): read A1 (A0 dead); stage Ah0(t+2)->cur (A0 region dead)
        PHASE(curoff, 1, 1, 1, 0, STAGE(cur, 0, 0, t + 2), (void)0, 1);
        // ph3 (1,0): no reads (frags resident); stage Bh0(t+2)->cur;
        //            wait lands Ah0/Bh0(t+1)
        PHASE(curoff, 1, 0, 0, 0, STAGE(cur, 1, 0, t + 2), VMWAIT(8), 0);
    }
    VMWAIT(0);   // drain dummy stages before LDS goes out of scope

    // Epilogue: C/D mapping col=lane&15, row=(lane>>4)*4+j (verified round 0)
    const float scale = scale_ptr ? *scale_ptr : 1.0f;
    const int g4 = (lane >> 4) * 4;
#pragma unroll
    for (int mi = 0; mi < 8; ++mi) {
        const int row0 = bm * 256 + wm * 128 + mi * 16 + g4;
#pragma unroll
        for (int ni = 0; ni < 4; ++ni) {
            const int col = bn * 256 + wn * 64 + ni * 16 + r15;
            float bcol = (BIAS_MODE == 1) ? bias[col] : 0.0f;
#pragma unroll
            for (int j = 0; j < 4; ++j) {
                float v = acc[mi][ni][j] * scale;
                if (BIAS_MODE == 1) v += bcol;
                if (BIAS_MODE == 2) v += bias[row0 + j];
                if (ROWSCALE)       v *= rowscale[(long)bz * M + row0 + j];
                const long idx = (long)bz * sC + (long)(row0 + j) * N + col;
                if (OUT_BF16) ((ushort*)C)[idx] = f2b(v);
                else          ((float*)C)[idx]  = v;
            }
        }
    }
}

// ---------------------------------------------------------------------------
// rowmax over 512 (bf16) + sigmoid -> boost = 1 + sigmoid(max)
// ---------------------------------------------------------------------------
__global__ void rowmax_boost(const ushort* __restrict__ punt, float* __restrict__ boost) {
    const long row = blockIdx.x;
    const int tid = threadIdx.x;
    __shared__ float sm[4];
    ushort2 p2 = *(const ushort2*)(punt + row * RR + tid * 2);
    float m = fmaxf(b2f(p2.x), b2f(p2.y));
#pragma unroll
    for (int o = 32; o > 0; o >>= 1) m = fmaxf(m, __shfl_down(m, o));
    if ((tid & 63) == 0) sm[tid >> 6] = m;
    __syncthreads();
    if (tid == 0) {
        m = fmaxf(fmaxf(sm[0], sm[1]), fmaxf(sm[2], sm[3]));
        boost[row] = 1.0f + 1.0f / (1.0f + __expf(-m));
    }
}

// ---------------------------------------------------------------------------
// Row softmax: bf16 [rows,1024] -> bf16 [rows,1024]
// ---------------------------------------------------------------------------
__global__ void softmax_rows(const ushort* __restrict__ S, ushort* __restrict__ P) {
    const long row = blockIdx.x;
    const int tid = threadIdx.x;
    __shared__ float sm[4];
    ushort4 xr = *(const ushort4*)(S + row * 1024 + tid * 4);
    float x0 = b2f(xr.x), x1 = b2f(xr.y), x2 = b2f(xr.z), x3 = b2f(xr.w);
    float m = fmaxf(fmaxf(x0, x1), fmaxf(x2, x3));
#pragma unroll
    for (int o = 32; o > 0; o >>= 1) m = fmaxf(m, __shfl_down(m, o));
    if ((tid & 63) == 0) sm[tid >> 6] = m;
    __syncthreads();
    m = fmaxf(fmaxf(sm[0], sm[1]), fmaxf(sm[2], sm[3]));
    __syncthreads();
    float e0 = __expf(x0 - m), e1 = __expf(x1 - m);
    float e2 = __expf(x2 - m), e3 = __expf(x3 - m);
    float s = e0 + e1 + e2 + e3;
#pragma unroll
    for (int o = 32; o > 0; o >>= 1) s += __shfl_down(s, o);
    if ((tid & 63) == 0) sm[tid >> 6] = s;
    __syncthreads();
    s = sm[0] + sm[1] + sm[2] + sm[3];
    const float inv = 1.0f / s;
    ushort4 o4;
    o4.x = f2b(e0 * inv); o4.y = f2b(e1 * inv);
    o4.z = f2b(e2 * inv); o4.w = f2b(e3 * inv);
    *(ushort4*)(P + row * 1024 + tid * 4) = o4;
}

// ---------------------------------------------------------------------------
// LayerNorm over D (bf16 input) + mean-pool over S (atomicAdd into out[b][d])
// ---------------------------------------------------------------------------
__global__ void ln_pool(const ushort* __restrict__ x, const float* __restrict__ gamma,
                        const float* __restrict__ beta, float* __restrict__ out) {
    const int b = blockIdx.y, chunk = blockIdx.x, tid = threadIdx.x;
    __shared__ float sm[8];
    float4 g  = *(const float4*)(gamma + tid * 4);
    float4 be = *(const float4*)(beta + tid * 4);
    float a0 = 0, a1 = 0, a2 = 0, a3 = 0;
    for (int s = chunk * 64; s < chunk * 64 + 64; ++s) {
        ushort4 xr = *(const ushort4*)(x + ((long)b * SS + s) * DD + tid * 4);
        float x0 = b2f(xr.x), x1 = b2f(xr.y), x2 = b2f(xr.z), x3 = b2f(xr.w);
        float ls = x0 + x1 + x2 + x3;
        float lq = x0 * x0 + x1 * x1 + x2 * x2 + x3 * x3;
#pragma unroll
        for (int o = 32; o > 0; o >>= 1) { ls += __shfl_down(ls, o); lq += __shfl_down(lq, o); }
        if ((tid & 63) == 0) { sm[(tid >> 6) * 2] = ls; sm[(tid >> 6) * 2 + 1] = lq; }
        __syncthreads();
        const float ts = sm[0] + sm[2] + sm[4] + sm[6];
        const float tq = sm[1] + sm[3] + sm[5] + sm[7];
        __syncthreads();
        const float mu  = ts * (1.0f / DD);
        const float var = tq * (1.0f / DD) - mu * mu;
        const float rs  = rsqrtf(var + 1e-5f);
        a0 += (x0 - mu) * rs * g.x + be.x;
        a1 += (x1 - mu) * rs * g.y + be.y;
        a2 += (x2 - mu) * rs * g.z + be.z;
        a3 += (x3 - mu) * rs * g.w + be.w;
    }
    const float is = 1.0f / SS;
    atomicAdd(out + (long)b * DD + tid * 4 + 0, a0 * is);
    atomicAdd(out + (long)b * DD + tid * 4 + 1, a1 * is);
    atomicAdd(out + (long)b * DD + tid * 4 + 2, a2 * is);
    atomicAdd(out + (long)b * DD + tid * 4 + 3, a3 * is);
}

// ---------------------------------------------------------------------------
// Workspace layout (bytes)
// ---------------------------------------------------------------------------
#define OFF_XBF   0ul            /* 32MB bf16 X [16384,1024]; later reused for P */
#define OFF_WQT   33554432ul     /* 2MB  Wq^T [1024,1024] */
#define OFF_WKT   35651584ul
#define OFF_WVT   37748736ul
#define OFF_WPRT  39845888ul     /* 1.5MB Wpr^T [1024,768] */
#define OFF_EMBB  41418752ul     /* 0.75MB emb bf16 [512,768] */
#define OFF_Q     42205184ul     /* 32MB Q bf16 */
#define OFF_K     75759616ul     /* 32MB K bf16 */
#define OFF_VT    109314048ul    /* 32MB V^T bf16 [16][1024(D)][1024(S)] */
#define OFF_RP    142868480ul    /* 1MB  Rp bf16 [512,1024] */
#define OFF_BOOST 143917056ul    /* 64KB boost fp32 [16384] */
#define OFF_BIG   143982592ul    /* 32MB bf16: punt -> scores -> xboost */

extern "C" void kernel_launch(void* const* d_in, const int* in_sizes, int n_in,
                              void* d_out, int out_size, void* d_ws, size_t ws_size,
                              hipStream_t stream) {
    (void)in_sizes; (void)n_in; (void)ws_size;
    const float* lstm  = (const float*)d_in[0];
    const float* emb   = (const float*)d_in[1];
    const float* Wq    = (const float*)d_in[2];
    const float* bq    = (const float*)d_in[3];
    const float* Wk    = (const float*)d_in[4];
    const float* bk    = (const float*)d_in[5];
    const float* Wv    = (const float*)d_in[6];
    const float* bv    = (const float*)d_in[7];
    const float* Wpr   = (const float*)d_in[8];
    const float* bpr   = (const float*)d_in[9];
    const float* esc   = (const float*)d_in[10];
    const float* gamma = (const float*)d_in[11];
    const float* beta  = (const float*)d_in[12];
    float* out = (float*)d_out;

    char* ws = (char*)d_ws;
    ushort* Xbf  = (ushort*)(ws + OFF_XBF);
    ushort* Wqt  = (ushort*)(ws + OFF_WQT);
    ushort* Wkt  = (ushort*)(ws + OFF_WKT);
    ushort* Wvt  = (ushort*)(ws + OFF_WVT);
    ushort* Wprt = (ushort*)(ws + OFF_WPRT);
    ushort* Embb = (ushort*)(ws + OFF_EMBB);
    ushort* Qb   = (ushort*)(ws + OFF_Q);
    ushort* Kb   = (ushort*)(ws + OFF_K);
    ushort* Vt   = (ushort*)(ws + OFF_VT);
    ushort* Rp   = (ushort*)(ws + OFF_RP);
    float*  boost= (float*)(ws + OFF_BOOST);
    ushort* bigU = (ushort*)(ws + OFF_BIG);   // bf16 punt / scores / xboost
    ushort* P    = (ushort*)(ws + OFF_XBF);   // alias: X no longer needed by then

    hipMemsetAsync(d_out, 0, (size_t)out_size * sizeof(float), stream);

    // casts
    {
        long n4 = (long)BB * SS * DD / 4;
        cast_f32_bf16<<<dim3((n4 + 255) / 256), dim3(256), 0, stream>>>(lstm, Xbf, n4);
        long e4 = (long)RR * EE / 4;
        cast_f32_bf16<<<dim3((e4 + 255) / 256), dim3(256), 0, stream>>>(emb, Embb, e4);
        transpose_cast<<<dim3(32, 32), dim3(32, 8), 0, stream>>>(Wq, Wqt, 1024, 1024);
        transpose_cast<<<dim3(32, 32), dim3(32, 8), 0, stream>>>(Wk, Wkt, 1024, 1024);
        transpose_cast<<<dim3(32, 32), dim3(32, 8), 0, stream>>>(Wv, Wvt, 1024, 1024);
        transpose_cast<<<dim3(32, 24), dim3(32, 8), 0, stream>>>(Wpr, Wprt, 768, 1024);
    }

    // Rp = emb @ Wpr + bpr   [512,1024] bf16
    gemm8<1, true, false><<<dim3(4, 2, 1), 512, 0, stream>>>(
        Embb, Wprt, Rp, bpr, nullptr, nullptr, 1024, 768, 512, 0, 0, 0);
    // Q = X @ Wq + bq   [16384,1024] bf16
    gemm8<1, true, false><<<dim3(4, 64, 1), 512, 0, stream>>>(
        Xbf, Wqt, Qb, bq, nullptr, nullptr, 1024, 1024, 16384, 0, 0, 0);
    // K = X @ Wk + bk
    gemm8<1, true, false><<<dim3(4, 64, 1), 512, 0, stream>>>(
        Xbf, Wkt, Kb, bk, nullptr, nullptr, 1024, 1024, 16384, 0, 0, 0);
    // Vt[b] = (X_b @ Wv)^T + bv (per-row bias)  [16][D][S]
    gemm8<2, true, false><<<dim3(4, 4, 16), 512, 0, stream>>>(
        Wvt, Xbf, Vt, bv, nullptr, nullptr, 1024, 1024, 1024,
        0, (long)SS * DD, (long)DD * SS);
    // punt = Q @ Rp^T  [16384,512] bf16 (in BIG)
    gemm8<0, true, false><<<dim3(2, 64, 1), 512, 0, stream>>>(
        Qb, Rp, bigU, nullptr, nullptr, nullptr, 512, 1024, 16384, 0, 0, 0);
    // boost = 1 + sigmoid(rowmax(punt))
    rowmax_boost<<<dim3(16384), 256, 0, stream>>>(bigU, boost);
    // scores[b] = Q_b @ K_b^T * escala  [16][1024][1024] bf16 (in BIG)
    gemm8<0, true, false><<<dim3(4, 4, 16), 512, 0, stream>>>(
        Qb, Kb, bigU, nullptr, nullptr, esc, 1024, 1024, 1024,
        (long)SS * DD, (long)SS * DD, (long)SS * SS);
    // P = softmax(scores) bf16 (into Xbf region)
    softmax_rows<<<dim3(16384), 256, 0, stream>>>(bigU, P);
    // xboost[b] = (P_b @ V_b) * boost  bf16 (in BIG, overwrites scores)
    gemm8<0, true, true><<<dim3(4, 4, 16), 512, 0, stream>>>(
        P, Vt, bigU, nullptr, boost, nullptr, 1024, 1024, 1024,
        (long)SS * SS, (long)DD * SS, (long)SS * DD);
    // LN + mean pool
    ln_pool<<<dim3(16, 16), 256, 0, stream>>>(bigU, gamma, beta, out);
}

// Round 8
// 410.655 us; speedup vs baseline: 1.4134x; 1.0696x over previous
//
#include <hip/hip_runtime.h>

// ---------------------------------------------------------------------------
// RiskAttention: q/k/v proj -> lexicon relevance -> self-attn -> boost -> LN -> pool
// B=16 S=1024 D=1024 R=512 E=768, fp32 in/out, bf16 MFMA compute.
// Round 7: phase-reordered 8-phase GEMM + bf16 intermediates (439us).
// Round 8: ln_pool was 47us (top dispatch): 256 blocks, 64 serial rows x 2
//   barriers each, 10% occupancy -> latency-bound. Rewrite: wave-autonomous
//   rows (8/wave, preloaded), shfl-xor butterfly reduce, zero in-loop barriers,
//   gamma/beta factored out of the S-loop. GEMM untouched (clean attribution).
// ---------------------------------------------------------------------------

#define BB 16
#define SS 1024
#define DD 1024
#define RR 512
#define EE 768

typedef __attribute__((ext_vector_type(4))) float f32x4;
typedef __attribute__((ext_vector_type(8))) __bf16 bf16x8;
typedef __attribute__((ext_vector_type(4))) unsigned int u32x4;

typedef __attribute__((address_space(1))) const void g_void;
typedef __attribute__((address_space(3))) void l_void;

__device__ __forceinline__ ushort f2b(float x) {
    unsigned u = __float_as_uint(x);
    u += 0x7fffu + ((u >> 16) & 1u);   // RNE
    return (ushort)(u >> 16);
}
__device__ __forceinline__ float b2f(ushort u) {
    return __uint_as_float((unsigned)u << 16);
}

// ---------------------------------------------------------------------------
// Casts
// ---------------------------------------------------------------------------
__global__ void cast_f32_bf16(const float* __restrict__ in, ushort* __restrict__ out, long n4) {
    long i = (long)blockIdx.x * blockDim.x + threadIdx.x;
    if (i >= n4) return;
    float4 v = *(const float4*)(in + i * 4);
    ushort4 o;
    o.x = f2b(v.x); o.y = f2b(v.y); o.z = f2b(v.z); o.w = f2b(v.w);
    *(ushort4*)(out + i * 4) = o;
}

// in [rows, cols] fp32 -> out [cols, rows] bf16
__global__ void transpose_cast(const float* __restrict__ in, ushort* __restrict__ out,
                               int rows, int cols) {
    __shared__ float tile[32][33];
    const int bx = blockIdx.x * 32;   // col base
    const int by = blockIdx.y * 32;   // row base
    const int tx = threadIdx.x;       // 0..31
    const int ty = threadIdx.y;       // 0..7
#pragma unroll
    for (int i = 0; i < 32; i += 8)
        tile[ty + i][tx] = in[(long)(by + ty + i) * cols + bx + tx];
    __syncthreads();
#pragma unroll
    for (int i = 0; i < 32; i += 8)
        out[(long)(bx + ty + i) * rows + by + tx] = f2b(tile[tx][ty + i]);
}

// ---------------------------------------------------------------------------
// 8-phase 256x256 BT-GEMM: C[z][m][n] = sum_k A[z][m][k]*B[z][n][k] (bf16 row-major)
// 8 waves (2Mx4N), BK=64, 2-deep LDS dbuf, XOR-swizzled LDS, counted vmcnt,
// inline-asm ds_read_b128 fragment loads. B-frags dual-buffered across nh.
// ---------------------------------------------------------------------------

#define VMWAIT(N) asm volatile("s_waitcnt vmcnt(" #N ")" ::: "memory")
#define BARRIER() asm volatile("s_barrier" ::: "memory")
#define LGKM0()   asm volatile("s_waitcnt lgkmcnt(0)" ::: "memory")
#define DSR(dst, addr, imm) \
    asm volatile("ds_read_b128 %0, %1 offset:" #imm : "=v"(dst) : "v"(addr))

// Stage half-tile (mat: 0=A,1=B; h: 0/1) of K-tile ti_ into LDS buffer buf.
// Linear LDS dest (wave-uniform base + lane*16B); swizzle applied on the
// per-lane GLOBAL source column: c = ((lane&7)^(lane>>3))*8.
// A-half h rows: {i*128 + h*64 + wave*8 + srow}                (= A phase reads)
// B-half h rows: {(i*2+(wave>>2))*64 + h*32 + (wave&3)*8 + srow} (= B phase reads)
#define STAGE(buf, mat, h, ti_) do {                                               \
    const int ti__ = (ti_) < (T - 1) ? (ti_) : (T - 1);                            \
    const ushort* sp__ = (mat) ? Bb : Ab;                                          \
    const long kb__ = (long)ti__ * 64 + scol;                                      \
    _Pragma("unroll")                                                              \
    for (int i__ = 0; i__ < 2; ++i__) {                                            \
        const int row0__ = (mat)                                                   \
            ? ((i__ * 2 + (wave >> 2)) * 64 + (h) * 32 + (wave & 3) * 8)           \
            : (i__ * 128 + (h) * 64 + wave * 8);                                   \
        __builtin_amdgcn_global_load_lds(                                          \
            (g_void*)(sp__ + (long)(row0__ + srow) * K + kb__),                    \
            (l_void*)(&lds[(buf) * 2 + (mat)][row0__ * 64]), 16, 0, 0);            \
    }                                                                              \
} while (0)

// One phase: quadrant (mh, nh). RA: read A-frags for mh (8 DSR).
// RB: read B-frags for nh into bfr[nh] (4 DSR). LG: lgkmcnt(0)+sched_barrier
// fence (rule #18) -- only when this phase issued fresh ds_reads.
// Two bases per matrix: k-half 0 at col (k0^xo), k-half 1 at (k0^xo)^64B (XOR).
#define PHASE(curoff_, mh, nh, RA, RB, STAGE_STMT, WAIT_STMT, LG) do {             \
    if (RA) {                                                                      \
        const unsigned a0__ = abase0 + (curoff_) + (mh) * 8192;                    \
        const unsigned a1__ = abase1 + (curoff_) + (mh) * 8192;                    \
        DSR(af[0][0], a0__, 0);    DSR(af[0][1], a1__, 0);                         \
        DSR(af[1][0], a0__, 2048); DSR(af[1][1], a1__, 2048);                      \
        DSR(af[2][0], a0__, 4096); DSR(af[2][1], a1__, 4096);                      \
        DSR(af[3][0], a0__, 6144); DSR(af[3][1], a1__, 6144);                      \
    }                                                                              \
    if (RB) {                                                                      \
        const unsigned b0__ = bbase0 + (curoff_) + (nh) * 4096;                    \
        const unsigned b1__ = bbase1 + (curoff_) + (nh) * 4096;                    \
        DSR(bfr[nh][0][0], b0__, 0);    DSR(bfr[nh][0][1], b1__, 0);               \
        DSR(bfr[nh][1][0], b0__, 2048); DSR(bfr[nh][1][1], b1__, 2048);            \
    }                                                                              \
    STAGE_STMT;                                                                    \
    BARRIER();                                                                     \
    if (LG) { LGKM0(); __builtin_amdgcn_sched_barrier(0); }                        \
    __builtin_amdgcn_s_setprio(1);                                                 \
    _Pragma("unroll")                                                              \
    for (int mi = 0; mi < 4; ++mi)                                                 \
        _Pragma("unroll")                                                          \
        for (int ni = 0; ni < 2; ++ni) {                                           \
            acc[(mh) * 4 + mi][(nh) * 2 + ni] = __builtin_amdgcn_mfma_f32_16x16x32_bf16( \
                __builtin_bit_cast(bf16x8, af[mi][0]),                             \
                __builtin_bit_cast(bf16x8, bfr[nh][ni][0]),                        \
                acc[(mh) * 4 + mi][(nh) * 2 + ni], 0, 0, 0);                       \
            acc[(mh) * 4 + mi][(nh) * 2 + ni] = __builtin_amdgcn_mfma_f32_16x16x32_bf16( \
                __builtin_bit_cast(bf16x8, af[mi][1]),                             \
                __builtin_bit_cast(bf16x8, bfr[nh][ni][1]),                        \
                acc[(mh) * 4 + mi][(nh) * 2 + ni], 0, 0, 0);                       \
        }                                                                          \
    __builtin_amdgcn_s_setprio(0);                                                 \
    WAIT_STMT;                                                                     \
    BARRIER();                                                                     \
} while (0)

template <int BIAS_MODE, bool OUT_BF16, bool ROWSCALE>
__global__ __launch_bounds__(512, 2) void gemm8(
    const ushort* __restrict__ A, const ushort* __restrict__ B, void* __restrict__ C,
    const float* __restrict__ bias, const float* __restrict__ rowscale,
    const float* __restrict__ scale_ptr,
    int N, int K, int M, long sA, long sB, long sC)
{
    __shared__ ushort lds[4][16384];   // [buf*2 + mat][256 rows * 64 k] = 128 KiB
    const int tid  = threadIdx.x;
    const int wave = tid >> 6;
    const int lane = tid & 63;
    const int wm = wave >> 2, wn = wave & 3;      // 2 x 4 wave grid

    // XCD-chunked bijective block swizzle (all launches have nwg % 8 == 0)
    const int nx = gridDim.x, ny = gridDim.y;
    long flat = blockIdx.x + (long)nx * (blockIdx.y + (long)ny * blockIdx.z);
    const long nwg = (long)nx * ny * gridDim.z;
    const long cpx = nwg >> 3;
    flat = (flat & 7) * cpx + (flat >> 3);
    const int bn = (int)(flat % nx);
    const long r1 = flat / nx;
    const int bm = (int)(r1 % ny);
    const int bz = (int)(r1 / ny);

    const ushort* Ab = A + (long)bz * sA + (long)bm * 256 * K;
    const ushort* Bb = B + (long)bz * sB + (long)bn * 256 * K;
    const int T = K >> 6;

    const int srow = lane >> 3;                    // row within 8-row wave chunk
    const int scol = ((lane & 7) ^ srow) * 8;      // pre-swizzled source column

    // LDS byte bases for fragment reads (low 32 bits of generic ptr = LDS offset)
    const unsigned lb = (unsigned)(unsigned long long)(void*)&lds[0][0];
    const int r15 = lane & 15;
    const int k0  = (lane >> 4) * 8;               // k-element offset of fragment
    const int xo  = (lane & 7) * 8;                // row-swizzle (row&7 == lane&7)
    const unsigned colA = (unsigned)((k0 ^ xo) * 2);          // k-half 0, bytes
    const unsigned arow = (unsigned)((wm * 128 + r15) * 128);
    const unsigned brow = (unsigned)((wn * 64 + r15) * 128);
    const unsigned abase0 = lb + arow + colA;
    const unsigned abase1 = lb + arow + (colA ^ 64u);         // k-half 1 (XOR!)
    const unsigned bbase0 = lb + 32768u + brow + colA;
    const unsigned bbase1 = lb + 32768u + brow + (colA ^ 64u);

    f32x4 acc[8][4];
#pragma unroll
    for (int i = 0; i < 8; ++i)
#pragma unroll
        for (int j = 0; j < 4; ++j) acc[i][j] = (f32x4){0.f, 0.f, 0.f, 0.f};

    u32x4 af[4][2], bfr[2][2][2];   // af[mi][kh]; bfr[nh][ni][kh]

    // Prologue: tile0 {A0,B0,B1,A1} + tile1 {A0,B0}  (6 stages = 12 loads/wave)
    STAGE(0, 0, 0, 0); STAGE(0, 1, 0, 0); STAGE(0, 1, 1, 0); STAGE(0, 0, 1, 0);
    STAGE(1, 0, 0, 1); STAGE(1, 1, 0, 1);
    VMWAIT(8);          // oldest 2 stages (tile0 A0,B0) landed
    BARRIER();

    for (int t = 0; t < T; ++t) {
        const int cur = t & 1, nxt = cur ^ 1;
        const unsigned curoff = cur ? 65536u : 0u;
        // ph0 (0,0): read A0+B0; stage Ah1(t+1)->nxt; wait lands Bh1(t),Ah1(t)
        PHASE(curoff, 0, 0, 1, 1, STAGE(nxt, 0, 1, t + 1), VMWAIT(6), 1);
        // ph1 (0,1): read B1; stage Bh1(t+1)->nxt
        PHASE(curoff, 0, 1, 0, 1, STAGE(nxt, 1, 1, t + 1), (void)0, 1);
        // ph2 (1,1): read A1 (A0 dead); stage Ah0(t+2)->cur (A0 region dead)
        PHASE(curoff, 1, 1, 1, 0, STAGE(cur, 0, 0, t + 2), (void)0, 1);
        // ph3 (1,0): no reads (frags resident); stage Bh0(t+2)->cur;
        //            wait lands Ah0/Bh0(t+1)
        PHASE(curoff, 1, 0, 0, 0, STAGE(cur, 1, 0, t + 2), VMWAIT(8), 0);
    }
    VMWAIT(0);   // drain dummy stages before LDS goes out of scope

    // Epilogue: C/D mapping col=lane&15, row=(lane>>4)*4+j (verified round 0)
    const float scale = scale_ptr ? *scale_ptr : 1.0f;
    const int g4 = (lane >> 4) * 4;
#pragma unroll
    for (int mi = 0; mi < 8; ++mi) {
        const int row0 = bm * 256 + wm * 128 + mi * 16 + g4;
#pragma unroll
        for (int ni = 0; ni < 4; ++ni) {
            const int col = bn * 256 + wn * 64 + ni * 16 + r15;
            float bcol = (BIAS_MODE == 1) ? bias[col] : 0.0f;
#pragma unroll
            for (int j = 0; j < 4; ++j) {
                float v = acc[mi][ni][j] * scale;
                if (BIAS_MODE == 1) v += bcol;
                if (BIAS_MODE == 2) v += bias[row0 + j];
                if (ROWSCALE)       v *= rowscale[(long)bz * M + row0 + j];
                const long idx = (long)bz * sC + (long)(row0 + j) * N + col;
                if (OUT_BF16) ((ushort*)C)[idx] = f2b(v);
                else          ((float*)C)[idx]  = v;
            }
        }
    }
}

// ---------------------------------------------------------------------------
// rowmax over 512 (bf16) + sigmoid -> boost = 1 + sigmoid(max)
// ---------------------------------------------------------------------------
__global__ void rowmax_boost(const ushort* __restrict__ punt, float* __restrict__ boost) {
    const long row = blockIdx.x;
    const int tid = threadIdx.x;
    __shared__ float sm[4];
    ushort2 p2 = *(const ushort2*)(punt + row * RR + tid * 2);
    float m = fmaxf(b2f(p2.x), b2f(p2.y));
#pragma unroll
    for (int o = 32; o > 0; o >>= 1) m = fmaxf(m, __shfl_down(m, o));
    if ((tid & 63) == 0) sm[tid >> 6] = m;
    __syncthreads();
    if (tid == 0) {
        m = fmaxf(fmaxf(sm[0], sm[1]), fmaxf(sm[2], sm[3]));
        boost[row] = 1.0f + 1.0f / (1.0f + __expf(-m));
    }
}

// ---------------------------------------------------------------------------
// Row softmax: bf16 [rows,1024] -> bf16 [rows,1024]
// ---------------------------------------------------------------------------
__global__ void softmax_rows(const ushort* __restrict__ S, ushort* __restrict__ P) {
    const long row = blockIdx.x;
    const int tid = threadIdx.x;
    __shared__ float sm[4];
    ushort4 xr = *(const ushort4*)(S + row * 1024 + tid * 4);
    float x0 = b2f(xr.x), x1 = b2f(xr.y), x2 = b2f(xr.z), x3 = b2f(xr.w);
    float m = fmaxf(fmaxf(x0, x1), fmaxf(x2, x3));
#pragma unroll
    for (int o = 32; o > 0; o >>= 1) m = fmaxf(m, __shfl_down(m, o));
    if ((tid & 63) == 0) sm[tid >> 6] = m;
    __syncthreads();
    m = fmaxf(fmaxf(sm[0], sm[1]), fmaxf(sm[2], sm[3]));
    __syncthreads();
    float e0 = __expf(x0 - m), e1 = __expf(x1 - m);
    float e2 = __expf(x2 - m), e3 = __expf(x3 - m);
    float s = e0 + e1 + e2 + e3;
#pragma unroll
    for (int o = 32; o > 0; o >>= 1) s += __shfl_down(s, o);
    if ((tid & 63) == 0) sm[tid >> 6] = s;
    __syncthreads();
    s = sm[0] + sm[1] + sm[2] + sm[3];
    const float inv = 1.0f / s;
    ushort4 o4;
    o4.x = f2b(e0 * inv); o4.y = f2b(e1 * inv);
    o4.z = f2b(e2 * inv); o4.w = f2b(e3 * inv);
    *(ushort4*)(P + row * 1024 + tid * 4) = o4;
}

// ---------------------------------------------------------------------------
// LayerNorm over D (bf16) + mean-pool over S. Wave-autonomous: each wave owns
// 8 full rows (lane = 16 contiguous d), shfl-xor butterfly row reduce, no
// in-loop barriers. gamma applied once at the end; beta added by chunk 0.
// grid (chunk=16, b=16), block 512 = 8 waves (chunk = 64 rows).
// ---------------------------------------------------------------------------
__global__ __launch_bounds__(512) void ln_pool(
        const ushort* __restrict__ x, const float* __restrict__ gamma,
        const float* __restrict__ beta, float* __restrict__ out) {
    const int b = blockIdx.y, chunk = blockIdx.x;
    const int tid = threadIdx.x, wave = tid >> 6, lane = tid & 63;
    __shared__ float red[8 * 1024];   // 32 KB, transposed slots
    const int s0 = chunk * 64 + wave * 8;
    const ushort* base = x + ((long)b * SS + s0) * DD + lane * 16;

    // preload all 8 rows (2 x b128 per row) for latency overlap
    u32x4 raw[8][2];
#pragma unroll
    for (int r = 0; r < 8; ++r) {
        raw[r][0] = *(const u32x4*)(base + (long)r * DD);
        raw[r][1] = *(const u32x4*)(base + (long)r * DD + 8);
    }

    float acc[16];
#pragma unroll
    for (int j = 0; j < 16; ++j) acc[j] = 0.f;

#pragma unroll
    for (int r = 0; r < 8; ++r) {
        float v[16];
#pragma unroll
        for (int h = 0; h < 2; ++h)
#pragma unroll
            for (int w = 0; w < 4; ++w) {
                const unsigned u = raw[r][h][w];
                v[h * 8 + w * 2]     = __uint_as_float(u << 16);          // even elem
                v[h * 8 + w * 2 + 1] = __uint_as_float(u & 0xffff0000u);  // odd elem
            }
        float s1 = 0.f, s2 = 0.f;
#pragma unroll
        for (int j = 0; j < 16; ++j) { s1 += v[j]; s2 += v[j] * v[j]; }
#pragma unroll
        for (int o = 1; o < 64; o <<= 1) {
            s1 += __shfl_xor(s1, o);
            s2 += __shfl_xor(s2, o);
        }
        const float mu = s1 * (1.0f / DD);
        const float rs = rsqrtf(s2 * (1.0f / DD) - mu * mu + 1e-5f);
#pragma unroll
        for (int j = 0; j < 16; ++j) acc[j] += (v[j] - mu) * rs;
    }

    // transposed store: d = lane*16+j  ->  slot j*64+lane (conflict-free)
#pragma unroll
    for (int j = 0; j < 16; ++j) red[wave * 1024 + j * 64 + lane] = acc[j];
    __syncthreads();

    // each thread folds 8 waves for 2 d-values, applies gamma (+beta once)
#pragma unroll
    for (int k = 0; k < 2; ++k) {
        const int d = tid * 2 + k;
        const int slot = (d & 15) * 64 + (d >> 4);
        float s = 0.f;
#pragma unroll
        for (int w = 0; w < 8; ++w) s += red[w * 1024 + slot];
        float outv = gamma[d] * s * (1.0f / SS);
        if (chunk == 0) outv += beta[d];
        atomicAdd(out + (long)b * DD + d, outv);
    }
}

// ---------------------------------------------------------------------------
// Workspace layout (bytes)
// ---------------------------------------------------------------------------
#define OFF_XBF   0ul            /* 32MB bf16 X [16384,1024]; later reused for P */
#define OFF_WQT   33554432ul     /* 2MB  Wq^T [1024,1024] */
#define OFF_WKT   35651584ul
#define OFF_WVT   37748736ul
#define OFF_WPRT  39845888ul     /* 1.5MB Wpr^T [1024,768] */
#define OFF_EMBB  41418752ul     /* 0.75MB emb bf16 [512,768] */
#define OFF_Q     42205184ul     /* 32MB Q bf16 */
#define OFF_K     75759616ul     /* 32MB K bf16 */
#define OFF_VT    109314048ul    /* 32MB V^T bf16 [16][1024(D)][1024(S)] */
#define OFF_RP    142868480ul    /* 1MB  Rp bf16 [512,1024] */
#define OFF_BOOST 143917056ul    /* 64KB boost fp32 [16384] */
#define OFF_BIG   143982592ul    /* 32MB bf16: punt -> scores -> xboost */

extern "C" void kernel_launch(void* const* d_in, const int* in_sizes, int n_in,
                              void* d_out, int out_size, void* d_ws, size_t ws_size,
                              hipStream_t stream) {
    (void)in_sizes; (void)n_in; (void)ws_size;
    const float* lstm  = (const float*)d_in[0];
    const float* emb   = (const float*)d_in[1];
    const float* Wq    = (const float*)d_in[2];
    const float* bq    = (const float*)d_in[3];
    const float* Wk    = (const float*)d_in[4];
    const float* bk    = (const float*)d_in[5];
    const float* Wv    = (const float*)d_in[6];
    const float* bv    = (const float*)d_in[7];
    const float* Wpr   = (const float*)d_in[8];
    const float* bpr   = (const float*)d_in[9];
    const float* esc   = (const float*)d_in[10];
    const float* gamma = (const float*)d_in[11];
    const float* beta  = (const float*)d_in[12];
    float* out = (float*)d_out;

    char* ws = (char*)d_ws;
    ushort* Xbf  = (ushort*)(ws + OFF_XBF);
    ushort* Wqt  = (ushort*)(ws + OFF_WQT);
    ushort* Wkt  = (ushort*)(ws + OFF_WKT);
    ushort* Wvt  = (ushort*)(ws + OFF_WVT);
    ushort* Wprt = (ushort*)(ws + OFF_WPRT);
    ushort* Embb = (ushort*)(ws + OFF_EMBB);
    ushort* Qb   = (ushort*)(ws + OFF_Q);
    ushort* Kb   = (ushort*)(ws + OFF_K);
    ushort* Vt   = (ushort*)(ws + OFF_VT);
    ushort* Rp   = (ushort*)(ws + OFF_RP);
    float*  boost= (float*)(ws + OFF_BOOST);
    ushort* bigU = (ushort*)(ws + OFF_BIG);   // bf16 punt / scores / xboost
    ushort* P    = (ushort*)(ws + OFF_XBF);   // alias: X no longer needed by then

    hipMemsetAsync(d_out, 0, (size_t)out_size * sizeof(float), stream);

    // casts
    {
        long n4 = (long)BB * SS * DD / 4;
        cast_f32_bf16<<<dim3((n4 + 255) / 256), dim3(256), 0, stream>>>(lstm, Xbf, n4);
        long e4 = (long)RR * EE / 4;
        cast_f32_bf16<<<dim3((e4 + 255) / 256), dim3(256), 0, stream>>>(emb, Embb, e4);
        transpose_cast<<<dim3(32, 32), dim3(32, 8), 0, stream>>>(Wq, Wqt, 1024, 1024);
        transpose_cast<<<dim3(32, 32), dim3(32, 8), 0, stream>>>(Wk, Wkt, 1024, 1024);
        transpose_cast<<<dim3(32, 32), dim3(32, 8), 0, stream>>>(Wv, Wvt, 1024, 1024);
        transpose_cast<<<dim3(32, 24), dim3(32, 8), 0, stream>>>(Wpr, Wprt, 768, 1024);
    }

    // Rp = emb @ Wpr + bpr   [512,1024] bf16
    gemm8<1, true, false><<<dim3(4, 2, 1), 512, 0, stream>>>(
        Embb, Wprt, Rp, bpr, nullptr, nullptr, 1024, 768, 512, 0, 0, 0);
    // Q = X @ Wq + bq   [16384,1024] bf16
    gemm8<1, true, false><<<dim3(4, 64, 1), 512, 0, stream>>>(
        Xbf, Wqt, Qb, bq, nullptr, nullptr, 1024, 1024, 16384, 0, 0, 0);
    // K = X @ Wk + bk
    gemm8<1, true, false><<<dim3(4, 64, 1), 512, 0, stream>>>(
        Xbf, Wkt, Kb, bk, nullptr, nullptr, 1024, 1024, 16384, 0, 0, 0);
    // Vt[b] = (X_b @ Wv)^T + bv (per-row bias)  [16][D][S]
    gemm8<2, true, false><<<dim3(4, 4, 16), 512, 0, stream>>>(
        Wvt, Xbf, Vt, bv, nullptr, nullptr, 1024, 1024, 1024,
        0, (long)SS * DD, (long)DD * SS);
    // punt = Q @ Rp^T  [16384,512] bf16 (in BIG)
    gemm8<0, true, false><<<dim3(2, 64, 1), 512, 0, stream>>>(
        Qb, Rp, bigU, nullptr, nullptr, nullptr, 512, 1024, 16384, 0, 0, 0);
    // boost = 1 + sigmoid(rowmax(punt))
    rowmax_boost<<<dim3(16384), 256, 0, stream>>>(bigU, boost);
    // scores[b] = Q_b @ K_b^T * escala  [16][1024][1024] bf16 (in BIG)
    gemm8<0, true, false><<<dim3(4, 4, 16), 512, 0, stream>>>(
        Qb, Kb, bigU, nullptr, nullptr, esc, 1024, 1024, 1024,
        (long)SS * DD, (long)SS * DD, (long)SS * SS);
    // P = softmax(scores) bf16 (into Xbf region)
    softmax_rows<<<dim3(16384), 256, 0, stream>>>(bigU, P);
    // xboost[b] = (P_b @ V_b) * boost  bf16 (in BIG, overwrites scores)
    gemm8<0, true, true><<<dim3(4, 4, 16), 512, 0, stream>>>(
        P, Vt, bigU, nullptr, boost, nullptr, 1024, 1024, 1024,
        (long)SS * SS, (long)DD * SS, (long)SS * DD);
    // LN + mean pool
    ln_pool<<<dim3(16, 16), 512, 0, stream>>>(bigU, gamma, beta, out);
}